// Round 1
// baseline (4704.364 us; speedup 1.0000x reference)
//
#include <hip/hip_runtime.h>
#include <math.h>

constexpr int kB   = 32;
constexpr int kN   = 512;
constexpr int kC   = 512;
constexpr int kH   = 8;
constexpr int kDH  = 64;
constexpr int kAD  = 8;
constexpr int kMLP = 4096;
constexpr int kBN  = kB * kN;          // 16384 rows
constexpr float kEPS   = 1e-5f;
constexpr float kSCALE = 0.125f;       // DH^-0.5

__device__ __forceinline__ float qgelu_f(float x) {
    return x / (1.f + __expf(-1.702f * x));
}
__device__ __forceinline__ float gelu_f(float x) {
    return 0.5f * x * (1.f + erff(x * 0.70710678118654752f));
}

// ---------------------------------------------------------------------------
// residual add (optional) + LayerNorm. One block per row, 256 threads, C=512.
// ---------------------------------------------------------------------------
__global__ __launch_bounds__(256) void k_addln(
    const float* __restrict__ x, const float* __restrict__ pos,
    const float* __restrict__ g, const float* __restrict__ be,
    float* __restrict__ xout, float* __restrict__ hout)
{
    int row = blockIdx.x, tid = threadIdx.x;
    size_t base = (size_t)row * kC;
    float v0 = x[base + tid], v1 = x[base + tid + 256];
    if (pos) { v0 += pos[base + tid]; v1 += pos[base + tid + 256]; }
    if (xout) { xout[base + tid] = v0; xout[base + tid + 256] = v1; }
    float s = v0 + v1, q = v0 * v0 + v1 * v1;
    #pragma unroll
    for (int o = 32; o > 0; o >>= 1) {
        s += __shfl_down(s, o);
        q += __shfl_down(q, o);
    }
    __shared__ float ss[4], sq[4], mrs[2];
    int wv = tid >> 6, ln = tid & 63;
    if (!ln) { ss[wv] = s; sq[wv] = q; }
    __syncthreads();
    if (!tid) {
        float ts = ss[0] + ss[1] + ss[2] + ss[3];
        float tq = sq[0] + sq[1] + sq[2] + sq[3];
        float m = ts * (1.f / kC);
        float var = tq * (1.f / kC) - m * m;
        mrs[0] = m; mrs[1] = rsqrtf(var + kEPS);
    }
    __syncthreads();
    float m = mrs[0], r = mrs[1];
    hout[base + tid]       = (v0 - m) * r * g[tid] + be[tid];
    hout[base + tid + 256] = (v1 - m) * r * g[tid + 256] + be[tid + 256];
}

// ---------------------------------------------------------------------------
// fp32 tiled GEMM: out = [res +] act(A[M,K] @ W[K,Nc] [+ bias])
// 64x64 tile, BK=16, 256 threads, 4x4 per thread. ACT: 0 none, 1 qgelu, 2 gelu
// ---------------------------------------------------------------------------
template <int ACT, bool HASB, bool HASR>
__global__ __launch_bounds__(256) void k_gemm(
    const float* __restrict__ A, const float* __restrict__ W,
    const float* __restrict__ bias, const float* __restrict__ res,
    float* __restrict__ out, int M, int K, int Nc)
{
    __shared__ float As[16][68];   // [k][row], padded
    __shared__ float Bs[16][68];   // [k][col], padded
    int tid = threadIdx.x;
    int col0 = blockIdx.x * 64;
    int row0 = blockIdx.y * 64;
    int tx = tid & 15, ty = tid >> 4;

    int la_r = tid >> 2;          // 0..63 (A row)
    int la_k = (tid & 3) * 4;     // 0,4,8,12 (A k)
    int lb_k = tid >> 4;          // 0..15   (B k)
    int lb_c = (tid & 15) * 4;    // B col

    const float* Aptr = A + (size_t)(row0 + la_r) * K + la_k;
    const float* Wptr = W + (size_t)lb_k * Nc + col0 + lb_c;

    float acc[4][4] = {};
    for (int k0 = 0; k0 < K; k0 += 16) {
        float4 av = *(const float4*)(Aptr + k0);
        float4 bv = *(const float4*)(Wptr + (size_t)k0 * Nc);
        __syncthreads();
        As[la_k + 0][la_r] = av.x;
        As[la_k + 1][la_r] = av.y;
        As[la_k + 2][la_r] = av.z;
        As[la_k + 3][la_r] = av.w;
        *(float4*)&Bs[lb_k][lb_c] = bv;
        __syncthreads();
        #pragma unroll
        for (int kk = 0; kk < 16; kk++) {
            float4 a4 = *(const float4*)&As[kk][ty * 4];
            float4 b4 = *(const float4*)&Bs[kk][tx * 4];
            float aa[4] = {a4.x, a4.y, a4.z, a4.w};
            float bb[4] = {b4.x, b4.y, b4.z, b4.w};
            #pragma unroll
            for (int i = 0; i < 4; i++)
                #pragma unroll
                for (int j = 0; j < 4; j++)
                    acc[i][j] += aa[i] * bb[j];
        }
    }
    #pragma unroll
    for (int i = 0; i < 4; i++) {
        int row = row0 + ty * 4 + i;
        int col = col0 + tx * 4;
        float v[4] = {acc[i][0], acc[i][1], acc[i][2], acc[i][3]};
        if (HASB) {
            #pragma unroll
            for (int j = 0; j < 4; j++) v[j] += bias[col + j];
        }
        if (ACT == 1) {
            #pragma unroll
            for (int j = 0; j < 4; j++) v[j] = qgelu_f(v[j]);
        } else if (ACT == 2) {
            #pragma unroll
            for (int j = 0; j < 4; j++) v[j] = gelu_f(v[j]);
        }
        if (HASR) {
            const float4 r4 = *(const float4*)&res[(size_t)row * Nc + col];
            v[0] += r4.x; v[1] += r4.y; v[2] += r4.z; v[3] += r4.w;
        }
        float4 o4 = make_float4(v[0], v[1], v[2], v[3]);
        *(float4*)&out[(size_t)row * Nc + col] = o4;
    }
}

// ---------------------------------------------------------------------------
// flash attention over one batch-chunk. qkv rows: [bl*N+n][3*512] with
// q at +0, k at +512, v at +1024, head offset hh*64.
// block = 256 thr (4 waves); block handles (bl, hh, 32-query tile);
// wave handles 8 queries, lane = head dim.
// ---------------------------------------------------------------------------
__global__ __launch_bounds__(256) void k_attn(
    const float* __restrict__ qkv, float* __restrict__ o)
{
    int bid = blockIdx.x;
    int qt = bid & 15;
    int bh = bid >> 4;
    int hh = bh & 7;
    int bl = bh >> 3;
    int tid = threadIdx.x, wv = tid >> 6, ln = tid & 63;

    __shared__ float Qs[32 * 65];
    __shared__ float Ks[64 * 65];
    __shared__ float Vs[64 * 65];

    size_t base = (size_t)bl * kN * 1536;
    for (int i = tid; i < 32 * 64; i += 256) {
        int r = i >> 6, d = i & 63;
        Qs[r * 65 + d] = qkv[base + (size_t)(qt * 32 + r) * 1536 + hh * 64 + d];
    }
    __syncthreads();

    float qr[8], oa[8], mr[8], lr[8];
    #pragma unroll
    for (int qi = 0; qi < 8; qi++) {
        qr[qi] = Qs[(wv * 8 + qi) * 65 + ln];
        oa[qi] = 0.f; mr[qi] = -1e30f; lr[qi] = 0.f;
    }

    int krow = tid >> 4, kd = (tid & 15) * 4;
    const float* kbase = qkv + base + 512 + hh * 64 + kd;
    const float* vbase = qkv + base + 1024 + hh * 64 + kd;
    const float* kp = &Ks[ln * 65];
    const float* vp = &Vs[ln];

    for (int m0 = 0; m0 < kN; m0 += 64) {
        __syncthreads();
        #pragma unroll
        for (int ps = 0; ps < 4; ps++) {
            int r = ps * 16 + krow;
            float4 kv = *(const float4*)(kbase + (size_t)(m0 + r) * 1536);
            float4 vv = *(const float4*)(vbase + (size_t)(m0 + r) * 1536);
            Ks[r * 65 + kd + 0] = kv.x; Ks[r * 65 + kd + 1] = kv.y;
            Ks[r * 65 + kd + 2] = kv.z; Ks[r * 65 + kd + 3] = kv.w;
            Vs[r * 65 + kd + 0] = vv.x; Vs[r * 65 + kd + 1] = vv.y;
            Vs[r * 65 + kd + 2] = vv.z; Vs[r * 65 + kd + 3] = vv.w;
        }
        __syncthreads();
        #pragma unroll
        for (int qi = 0; qi < 8; qi++) {
            float s = 0.f;
            #pragma unroll
            for (int d = 0; d < 64; d++)
                s += __shfl(qr[qi], d) * kp[d];
            s *= kSCALE;
            float mx = s;
            #pragma unroll
            for (int off = 32; off; off >>= 1)
                mx = fmaxf(mx, __shfl_xor(mx, off));
            float mnew = fmaxf(mr[qi], mx);
            float p = __expf(s - mnew);
            float psum = p;
            #pragma unroll
            for (int off = 32; off; off >>= 1)
                psum += __shfl_xor(psum, off);
            float alpha = __expf(mr[qi] - mnew);
            mr[qi] = mnew;
            lr[qi] = lr[qi] * alpha + psum;
            float acc = oa[qi] * alpha;
            #pragma unroll
            for (int j = 0; j < 64; j++)
                acc += __shfl(p, j) * vp[j * 65];
            oa[qi] = acc;
        }
    }
    #pragma unroll
    for (int qi = 0; qi < 8; qi++) {
        int nq = qt * 32 + wv * 8 + qi;
        o[((size_t)bl * kN + nq) * kC + hh * 64 + ln] = oa[qi] / lr[qi];
    }
}

// ---------------------------------------------------------------------------
// Convpass down: cpa[row][a] = qgelu(h[row,:] @ dw[:,a] + db[a]); K=512
// thread = one (row, a). dw staged in LDS.
// ---------------------------------------------------------------------------
__global__ __launch_bounds__(256) void k_down(
    const float* __restrict__ h, const float* __restrict__ dw,
    const float* __restrict__ db, float* __restrict__ outp)
{
    __shared__ float sdw[kC * kAD];
    int t = threadIdx.x;
    for (int i = t; i < kC * kAD; i += 256) sdw[i] = dw[i];
    __syncthreads();
    int gt = blockIdx.x * 256 + t;
    int row = gt >> 3, a = gt & 7;
    const float* hr = h + (size_t)row * kC;
    float acc = 0.f;
    for (int k = 0; k < kC; k++) acc += hr[k] * sdw[k * kAD + a];
    outp[gt] = qgelu_f(acc + db[a]);
}

// ---------------------------------------------------------------------------
// 3x3x3 SAME conv over 8x8x8 grid, 8->8 channels, + bias, qgelu on output.
// One block per batch, thread = spatial position n (z,y,x), computes all 8 ao.
// ---------------------------------------------------------------------------
__global__ __launch_bounds__(512) void k_conv(
    const float* __restrict__ inp, const float* __restrict__ cw,
    const float* __restrict__ cb, float* __restrict__ outp)
{
    __shared__ float si[512 * 9];      // [n][a], padded to 9
    __shared__ float sw[8 * 8 * 27];
    int b = blockIdx.x, t = threadIdx.x;
    for (int i = t; i < 512 * 8; i += 512) {
        int n = i >> 3, a = i & 7;
        si[n * 9 + a] = inp[(size_t)b * 4096 + i];
    }
    for (int i = t; i < 1728; i += 512) sw[i] = cw[i];
    __syncthreads();
    int z = t >> 6, y = (t >> 3) & 7, xx = t & 7;
    float acc[8];
    #pragma unroll
    for (int ao = 0; ao < 8; ao++) acc[ao] = cb[ao];
    for (int dz = -1; dz <= 1; dz++) {
        int zz = z + dz; if ((unsigned)zz > 7u) continue;
        for (int dy = -1; dy <= 1; dy++) {
            int yy = y + dy; if ((unsigned)yy > 7u) continue;
            for (int dx = -1; dx <= 1; dx++) {
                int xn = xx + dx; if ((unsigned)xn > 7u) continue;
                int nn = zz * 64 + yy * 8 + xn;
                int wo = ((dz + 1) * 3 + (dy + 1)) * 3 + (dx + 1);
                #pragma unroll
                for (int ai = 0; ai < 8; ai++) {
                    float iv = si[nn * 9 + ai];
                    #pragma unroll
                    for (int ao = 0; ao < 8; ao++)
                        acc[ao] += iv * sw[(ao * 8 + ai) * 27 + wo];
                }
            }
        }
    }
    #pragma unroll
    for (int ao = 0; ao < 8; ao++)
        outp[(size_t)b * 4096 + t * 8 + ao] = qgelu_f(acc[ao]);
}

// ---------------------------------------------------------------------------
// Convpass up: xbuf[row][c] += pa[row,:] @ uw[:,c] + ub[c]; K=8, in-place add.
// One block per row.
// ---------------------------------------------------------------------------
__global__ __launch_bounds__(256) void k_up(
    const float* __restrict__ pa, const float* __restrict__ uw,
    const float* __restrict__ ub, float* __restrict__ xbuf)
{
    __shared__ float s[8];
    int row = blockIdx.x, t = threadIdx.x;
    if (t < 8) s[t] = pa[(size_t)row * kAD + t];
    __syncthreads();
    #pragma unroll
    for (int rep = 0; rep < 2; rep++) {
        int c = t + rep * 256;
        float acc = ub[c];
        #pragma unroll
        for (int a = 0; a < 8; a++) acc += s[a] * uw[a * kC + c];
        xbuf[(size_t)row * kC + c] += acc;
    }
}

// ---------------------------------------------------------------------------
extern "C" void kernel_launch(void* const* d_in, const int* in_sizes, int n_in,
                              void* d_out, int out_size, void* d_ws, size_t ws_size,
                              hipStream_t stream)
{
    const float* x     = (const float*)d_in[0];
    const float* pos   = (const float*)d_in[1];
    const float* ln1g  = (const float*)d_in[2];
    const float* ln1b  = (const float*)d_in[3];
    const float* qkvw  = (const float*)d_in[4];
    const float* projw = (const float*)d_in[5];
    const float* projb = (const float*)d_in[6];
    const float* dw1   = (const float*)d_in[7];
    const float* db1   = (const float*)d_in[8];
    const float* cw1   = (const float*)d_in[9];
    const float* cb1   = (const float*)d_in[10];
    const float* uw1   = (const float*)d_in[11];
    const float* ub1   = (const float*)d_in[12];
    const float* ln2g  = (const float*)d_in[13];
    const float* ln2b  = (const float*)d_in[14];
    const float* fw1   = (const float*)d_in[15];
    const float* fb1   = (const float*)d_in[16];
    const float* fw2   = (const float*)d_in[17];
    const float* fb2   = (const float*)d_in[18];
    const float* dw2   = (const float*)d_in[19];
    const float* db2   = (const float*)d_in[20];
    const float* cw2   = (const float*)d_in[21];
    const float* cb2   = (const float*)d_in[22];
    const float* uw2   = (const float*)d_in[23];
    const float* ub2   = (const float*)d_in[24];
    float* out = (float*)d_out;

    // workspace layout (floats):
    //  xbuf   : BN*C              (running residual)
    //  h      : BN*C              (LN output)
    //  big    : 4096*MLP          (QKV chunk / FFN-mid chunk)
    //  obuf   : 4096*C            (attention output chunk)
    //  cpa/cpb: BN*AD each        (convpass intermediates)
    //  total ~137 MiB
    float* ws   = (float*)d_ws;
    float* xbuf = ws;
    float* h    = xbuf + (size_t)kBN * kC;
    float* big  = h    + (size_t)kBN * kC;
    float* obuf = big  + (size_t)4096 * kMLP;
    float* cpa  = obuf + (size_t)4096 * kC;
    float* cpb  = cpa  + (size_t)kBN * kAD;

    // stage 1: x = x + pos; h = LN1(x)
    k_addln<<<kBN, 256, 0, stream>>>(x, pos, ln1g, ln1b, xbuf, h);

    // attention, chunked over batches (4 chunks x 8 batches = 4096 rows)
    const int ACH = 4;
    const int MRA = (kB / ACH) * kN;   // 4096
    for (int ci = 0; ci < ACH; ci++) {
        const float* hA = h + (size_t)ci * MRA * kC;
        k_gemm<0, false, false><<<dim3(3 * kC / 64, MRA / 64), 256, 0, stream>>>(
            hA, qkvw, nullptr, nullptr, big, MRA, kC, 3 * kC);
        k_attn<<<(kB / ACH) * kH * (kN / 32), 256, 0, stream>>>(big, obuf);
        k_gemm<0, true, true><<<dim3(kC / 64, MRA / 64), 256, 0, stream>>>(
            obuf, projw, projb,
            xbuf + (size_t)ci * MRA * kC, xbuf + (size_t)ci * MRA * kC,
            MRA, kC, kC);
    }

    // convpass 1 (uses h = LN1 output), accumulate into xbuf
    k_down<<<kBN * kAD / 256, 256, 0, stream>>>(h, dw1, db1, cpa);
    k_conv<<<kB, 512, 0, stream>>>(cpa, cw1, cb1, cpb);
    k_up<<<kBN, 256, 0, stream>>>(cpb, uw1, ub1, xbuf);

    // stage 2: h = LN2(xbuf)
    k_addln<<<kBN, 256, 0, stream>>>(xbuf, nullptr, ln2g, ln2b, nullptr, h);

    // convpass 2, accumulate into xbuf
    k_down<<<kBN * kAD / 256, 256, 0, stream>>>(h, dw2, db2, cpa);
    k_conv<<<kB, 512, 0, stream>>>(cpa, cw2, cb2, cpb);
    k_up<<<kBN, 256, 0, stream>>>(cpb, uw2, ub2, xbuf);

    // FFN, chunked over rows; gemm2 fuses residual (xbuf) and writes d_out
    const int FCH = 4;
    const int MRF = kBN / FCH;         // 4096
    for (int ci = 0; ci < FCH; ci++) {
        const float* hF = h + (size_t)ci * MRF * kC;
        k_gemm<2, true, false><<<dim3(kMLP / 64, MRF / 64), 256, 0, stream>>>(
            hF, fw1, fb1, nullptr, big, MRF, kC, kMLP);
        k_gemm<0, true, true><<<dim3(kC / 64, MRF / 64), 256, 0, stream>>>(
            big, fw2, fb2,
            xbuf + (size_t)ci * MRF * kC, out + (size_t)ci * MRF * kC,
            MRF, kMLP, kC);
    }
}

// Round 2
// 746.735 us; speedup vs baseline: 6.2999x; 6.2999x over previous
//
#include <hip/hip_runtime.h>
#include <math.h>

typedef __bf16 bf16_t;
typedef __bf16 bf16x8 __attribute__((ext_vector_type(8)));
typedef float f32x4 __attribute__((ext_vector_type(4)));

constexpr int kB   = 32;
constexpr int kN   = 512;
constexpr int kC   = 512;
constexpr int kH   = 8;
constexpr int kAD  = 8;
constexpr int kMLP = 4096;
constexpr int kBN  = kB * kN;          // 16384 rows
constexpr float kEPS   = 1e-5f;
constexpr float kSCALE = 0.125f;       // DH^-0.5

__device__ __forceinline__ float qgelu_f(float x) {
    return x / (1.f + __expf(-1.702f * x));
}
__device__ __forceinline__ float gelu_f(float x) {
    return 0.5f * x * (1.f + erff(x * 0.70710678118654752f));
}

// async global->LDS, 16 bytes per lane. LDS dest must be uniform-base+lane*16.
__device__ __forceinline__ void gld_lds16(const void* g, void* l) {
    typedef const __attribute__((address_space(1))) unsigned int* gp_t;
    typedef __attribute__((address_space(3))) unsigned int* lp_t;
    __builtin_amdgcn_global_load_lds((gp_t)(unsigned long long)g,
                                     (lp_t)(unsigned)(unsigned long long)l,
                                     16, 0, 0);
}

// ---------------------------------------------------------------------------
// residual add (optional) + LayerNorm -> fp32 xout (optional) + bf16 hout
// ---------------------------------------------------------------------------
__global__ __launch_bounds__(256) void k_addln(
    const float* __restrict__ x, const float* __restrict__ pos,
    const float* __restrict__ g, const float* __restrict__ be,
    float* __restrict__ xout, bf16_t* __restrict__ hout)
{
    int row = blockIdx.x, tid = threadIdx.x;
    size_t base = (size_t)row * kC;
    float v0 = x[base + tid], v1 = x[base + tid + 256];
    if (pos) { v0 += pos[base + tid]; v1 += pos[base + tid + 256]; }
    if (xout) { xout[base + tid] = v0; xout[base + tid + 256] = v1; }
    float s = v0 + v1, q = v0 * v0 + v1 * v1;
    #pragma unroll
    for (int o = 32; o > 0; o >>= 1) {
        s += __shfl_down(s, o);
        q += __shfl_down(q, o);
    }
    __shared__ float ss[4], sq[4], mrs[2];
    int wv = tid >> 6, ln = tid & 63;
    if (!ln) { ss[wv] = s; sq[wv] = q; }
    __syncthreads();
    if (!tid) {
        float ts = ss[0] + ss[1] + ss[2] + ss[3];
        float tq = sq[0] + sq[1] + sq[2] + sq[3];
        float m = ts * (1.f / kC);
        float var = tq * (1.f / kC) - m * m;
        mrs[0] = m; mrs[1] = rsqrtf(var + kEPS);
    }
    __syncthreads();
    float m = mrs[0], r = mrs[1];
    hout[base + tid]       = (bf16_t)((v0 - m) * r * g[tid] + be[tid]);
    hout[base + tid + 256] = (bf16_t)((v1 - m) * r * g[tid + 256] + be[tid + 256]);
}

// ---------------------------------------------------------------------------
// fp32 [K][N] weight -> bf16 [N][K] transposed copy
// ---------------------------------------------------------------------------
__global__ __launch_bounds__(256) void k_transpose(
    const float* __restrict__ w, bf16_t* __restrict__ wt, int K, int N)
{
    __shared__ float t[32][33];
    int n0 = blockIdx.x * 32, k0 = blockIdx.y * 32;
    int tx = threadIdx.x & 31, ty = threadIdx.x >> 5;   // 32 x 8
    #pragma unroll
    for (int j = 0; j < 32; j += 8)
        t[ty + j][tx] = w[(size_t)(k0 + ty + j) * N + n0 + tx];
    __syncthreads();
    #pragma unroll
    for (int j = 0; j < 32; j += 8)
        wt[(size_t)(n0 + ty + j) * K + k0 + tx] = (bf16_t)t[tx][ty + j];
}

// ---------------------------------------------------------------------------
// bf16 MFMA GEMM (m97 structure): C = [res +] act(A[M,K] @ Bt[N,K]^T [+ bias])
// 128x128 tile, BK=32, 256 threads = 4 waves, wave = 64x64 (4x4 MFMA tiles).
// OMODE: 0 = fp32 out, 1 = bf16 out, 2 = bf16 scatter to qkv blocked layout.
// ---------------------------------------------------------------------------
template <int ACT, bool HASB, bool HASR, int OMODE>
__global__ __launch_bounds__(256) void k_gemm(
    const bf16_t* __restrict__ A, const bf16_t* __restrict__ Bt,
    const float* __restrict__ bias, const float* __restrict__ res,
    void* __restrict__ outv, int M, int K, int Nc)
{
    __shared__ bf16_t As[128 * 32];
    __shared__ bf16_t Bs[128 * 32];
    int tid = threadIdx.x;
    int col0 = blockIdx.x * 128, row0 = blockIdx.y * 128;
    int w = tid >> 6, l = tid & 63;
    int rw0 = (w & 1) * 64, cw0 = (w >> 1) * 64;
    int lr = tid >> 2, lc = (tid & 3) * 8;

    f32x4 acc[4][4];
    #pragma unroll
    for (int i = 0; i < 4; i++)
        #pragma unroll
        for (int j = 0; j < 4; j++)
            acc[i][j] = (f32x4){0.f, 0.f, 0.f, 0.f};

    const bf16_t* Ag  = A  + (size_t)(row0 + lr) * K + lc;
    const bf16_t* Ag2 = A  + (size_t)(row0 + 64 + lr) * K + lc;
    const bf16_t* Bg  = Bt + (size_t)(col0 + lr) * K + lc;
    const bf16_t* Bg2 = Bt + (size_t)(col0 + 64 + lr) * K + lc;
    bf16_t* Asd  = &As[tid * 8];
    bf16_t* Asd2 = &As[2048 + tid * 8];
    bf16_t* Bsd  = &Bs[tid * 8];
    bf16_t* Bsd2 = &Bs[2048 + tid * 8];

    int am = rw0 + (l & 15);
    int bn = cw0 + (l & 15);
    int kq = (l >> 4) * 8;

    for (int k0 = 0; k0 < K; k0 += 32) {
        gld_lds16(Ag + k0, Asd);
        gld_lds16(Ag2 + k0, Asd2);
        gld_lds16(Bg + k0, Bsd);
        gld_lds16(Bg2 + k0, Bsd2);
        __syncthreads();
        bf16x8 af[4], bfr[4];
        #pragma unroll
        for (int mt = 0; mt < 4; mt++)
            af[mt] = *(const bf16x8*)&As[(am + mt * 16) * 32 + kq];
        #pragma unroll
        for (int nt = 0; nt < 4; nt++)
            bfr[nt] = *(const bf16x8*)&Bs[(bn + nt * 16) * 32 + kq];
        #pragma unroll
        for (int mt = 0; mt < 4; mt++)
            #pragma unroll
            for (int nt = 0; nt < 4; nt++)
                acc[mt][nt] = __builtin_amdgcn_mfma_f32_16x16x32_bf16(
                    af[mt], bfr[nt], acc[mt][nt], 0, 0, 0);
        __syncthreads();
    }

    #pragma unroll
    for (int mt = 0; mt < 4; mt++) {
        int rowb = row0 + rw0 + mt * 16 + (l >> 4) * 4;
        #pragma unroll
        for (int nt = 0; nt < 4; nt++) {
            int col = col0 + cw0 + nt * 16 + (l & 15);
            float bv = HASB ? bias[col] : 0.f;
            #pragma unroll
            for (int p = 0; p < 4; p++) {
                float v = acc[mt][nt][p] + bv;
                if (ACT == 1) v = qgelu_f(v);
                if (ACT == 2) v = gelu_f(v);
                int r = rowb + p;
                if (OMODE == 0) {
                    if (HASR) v += res[(size_t)r * Nc + col];
                    ((float*)outv)[(size_t)r * Nc + col] = v;
                } else if (OMODE == 1) {
                    ((bf16_t*)outv)[(size_t)r * Nc + col] = (bf16_t)v;
                } else {
                    int bb = r >> 9, n = r & 511;
                    int which = col >> 9, hd = (col >> 6) & 7, d = col & 63;
                    ((bf16_t*)outv)[(((size_t)(bb * 8 + hd) * 3 + which) << 15)
                                    + n * 64 + d] = (bf16_t)v;
                }
            }
        }
    }
}

// ---------------------------------------------------------------------------
// MFMA flash attention. qkvb layout: [(b*8+h)*3 + {q,k,v}][n][64] bf16.
// block = 256 thr (4 waves) = 128 queries; wave = 32 queries (2 m-tiles).
// K tile [64][72] LDS, V transposed to [64 d][72 key], P wave-private [32][72].
// ---------------------------------------------------------------------------
__global__ __launch_bounds__(256) void k_attn(
    const bf16_t* __restrict__ qkvb, bf16_t* __restrict__ obuf)
{
    __shared__ bf16_t Ks[64 * 72];
    __shared__ bf16_t Vt[64 * 72];
    __shared__ bf16_t Ps[4][32 * 72];
    int bid = blockIdx.x;
    int qb = bid & 3, h = (bid >> 2) & 7, b = bid >> 5;
    int t = threadIdx.x, w = t >> 6, l = t & 63;
    const bf16_t* qp = qkvb + (((size_t)(b * 8 + h) * 3) << 15);
    const bf16_t* kp = qp + (1 << 15);
    const bf16_t* vp = qp + (2 << 15);
    int q0 = qb * 128 + w * 32;
    int l15 = l & 15, lq = (l >> 4) * 8;

    bf16x8 aq[2][2];
    #pragma unroll
    for (int mt = 0; mt < 2; mt++)
        #pragma unroll
        for (int kh = 0; kh < 2; kh++)
            aq[mt][kh] = *(const bf16x8*)(qp + (size_t)(q0 + mt * 16 + l15) * 64
                                          + kh * 32 + lq);

    f32x4 o[2][4];
    float m_run[2][4], l_run[2][4];
    #pragma unroll
    for (int mt = 0; mt < 2; mt++) {
        #pragma unroll
        for (int dt = 0; dt < 4; dt++) o[mt][dt] = (f32x4){0.f, 0.f, 0.f, 0.f};
        #pragma unroll
        for (int p = 0; p < 4; p++) { m_run[mt][p] = -1e30f; l_run[mt][p] = 0.f; }
    }

    int sr = t >> 2, scc = (t & 3) * 16;
    for (int kt = 0; kt < 8; kt++) {
        if (kt) __syncthreads();
        {
            const bf16_t* ks = kp + (size_t)(kt * 64 + sr) * 64 + scc;
            *(uint4*)&Ks[sr * 72 + scc]     = *(const uint4*)ks;
            *(uint4*)&Ks[sr * 72 + scc + 8] = *(const uint4*)(ks + 8);
            const bf16_t* vs = vp + (size_t)(kt * 64 + sr) * 64 + scc;
            bf16x8 v0 = *(const bf16x8*)vs;
            bf16x8 v1 = *(const bf16x8*)(vs + 8);
            #pragma unroll
            for (int e = 0; e < 8; e++) {
                Vt[(scc + e) * 72 + sr]     = v0[e];
                Vt[(scc + 8 + e) * 72 + sr] = v1[e];
            }
        }
        __syncthreads();
        #pragma unroll
        for (int mt = 0; mt < 2; mt++) {
            f32x4 sc[4];
            #pragma unroll
            for (int nt = 0; nt < 4; nt++) sc[nt] = (f32x4){0.f, 0.f, 0.f, 0.f};
            #pragma unroll
            for (int nt = 0; nt < 4; nt++)
                #pragma unroll
                for (int kh = 0; kh < 2; kh++) {
                    bf16x8 bk = *(const bf16x8*)&Ks[(nt * 16 + l15) * 72
                                                    + kh * 32 + lq];
                    sc[nt] = __builtin_amdgcn_mfma_f32_16x16x32_bf16(
                        aq[mt][kh], bk, sc[nt], 0, 0, 0);
                }
            #pragma unroll
            for (int nt = 0; nt < 4; nt++)
                #pragma unroll
                for (int p = 0; p < 4; p++) sc[nt][p] *= kSCALE;

            float mx[4], alpha[4], rs[4];
            #pragma unroll
            for (int p = 0; p < 4; p++) {
                float m4 = fmaxf(fmaxf(sc[0][p], sc[1][p]),
                                 fmaxf(sc[2][p], sc[3][p]));
                #pragma unroll
                for (int off = 1; off < 16; off <<= 1)
                    m4 = fmaxf(m4, __shfl_xor(m4, off));
                float mn = fmaxf(m_run[mt][p], m4);
                alpha[p] = __expf(m_run[mt][p] - mn);
                m_run[mt][p] = mn;
                mx[p] = mn;
                rs[p] = 0.f;
            }
            int prow = mt * 16 + (l >> 4) * 4;
            #pragma unroll
            for (int nt = 0; nt < 4; nt++)
                #pragma unroll
                for (int p = 0; p < 4; p++) {
                    float pv = __expf(sc[nt][p] - mx[p]);
                    rs[p] += pv;
                    Ps[w][(prow + p) * 72 + nt * 16 + l15] = (bf16_t)pv;
                }
            #pragma unroll
            for (int p = 0; p < 4; p++) {
                float r = rs[p];
                #pragma unroll
                for (int off = 1; off < 16; off <<= 1)
                    r += __shfl_xor(r, off);
                l_run[mt][p] = l_run[mt][p] * alpha[p] + r;
                #pragma unroll
                for (int dt = 0; dt < 4; dt++) o[mt][dt][p] *= alpha[p];
            }
            bf16x8 ap[2];
            #pragma unroll
            for (int kh = 0; kh < 2; kh++)
                ap[kh] = *(const bf16x8*)&Ps[w][(mt * 16 + l15) * 72
                                                + kh * 32 + lq];
            #pragma unroll
            for (int dt = 0; dt < 4; dt++)
                #pragma unroll
                for (int kh = 0; kh < 2; kh++) {
                    bf16x8 bv = *(const bf16x8*)&Vt[(dt * 16 + l15) * 72
                                                    + kh * 32 + lq];
                    o[mt][dt] = __builtin_amdgcn_mfma_f32_16x16x32_bf16(
                        ap[kh], bv, o[mt][dt], 0, 0, 0);
                }
        }
    }
    #pragma unroll
    for (int mt = 0; mt < 2; mt++)
        #pragma unroll
        for (int dt = 0; dt < 4; dt++)
            #pragma unroll
            for (int p = 0; p < 4; p++) {
                int q = q0 + mt * 16 + (l >> 4) * 4 + p;
                int col = h * 64 + dt * 16 + l15;
                float v = o[mt][dt][p] / l_run[mt][p];
                obuf[((size_t)b * 512 + q) * 512 + col] = (bf16_t)v;
            }
}

// ---------------------------------------------------------------------------
// Convpass down (bf16 h): cpa[row][a] = qgelu(h[row,:] @ dw[:,a] + db[a])
// ---------------------------------------------------------------------------
__global__ __launch_bounds__(256) void k_down(
    const bf16_t* __restrict__ h, const float* __restrict__ dw,
    const float* __restrict__ db, float* __restrict__ outp)
{
    __shared__ float sdw[kC * kAD];
    int t = threadIdx.x;
    for (int i = t; i < kC * kAD; i += 256) sdw[i] = dw[i];
    __syncthreads();
    int gt = blockIdx.x * 256 + t;
    int row = gt >> 3, a = gt & 7;
    const bf16_t* hr = h + (size_t)row * kC;
    float acc = 0.f;
    for (int k = 0; k < kC; k++) acc += (float)hr[k] * sdw[k * kAD + a];
    outp[gt] = qgelu_f(acc + db[a]);
}

// ---------------------------------------------------------------------------
// 3x3x3 SAME conv over 8x8x8, 8->8 ch, + bias, qgelu
// ---------------------------------------------------------------------------
__global__ __launch_bounds__(512) void k_conv(
    const float* __restrict__ inp, const float* __restrict__ cw,
    const float* __restrict__ cb, float* __restrict__ outp)
{
    __shared__ float si[512 * 9];
    __shared__ float sw[8 * 8 * 27];
    int b = blockIdx.x, t = threadIdx.x;
    for (int i = t; i < 512 * 8; i += 512) {
        int n = i >> 3, a = i & 7;
        si[n * 9 + a] = inp[(size_t)b * 4096 + i];
    }
    for (int i = t; i < 1728; i += 512) sw[i] = cw[i];
    __syncthreads();
    int z = t >> 6, y = (t >> 3) & 7, xx = t & 7;
    float acc[8];
    #pragma unroll
    for (int ao = 0; ao < 8; ao++) acc[ao] = cb[ao];
    for (int dz = -1; dz <= 1; dz++) {
        int zz = z + dz; if ((unsigned)zz > 7u) continue;
        for (int dy = -1; dy <= 1; dy++) {
            int yy = y + dy; if ((unsigned)yy > 7u) continue;
            for (int dx = -1; dx <= 1; dx++) {
                int xn = xx + dx; if ((unsigned)xn > 7u) continue;
                int nn = zz * 64 + yy * 8 + xn;
                int wo = ((dz + 1) * 3 + (dy + 1)) * 3 + (dx + 1);
                #pragma unroll
                for (int ai = 0; ai < 8; ai++) {
                    float iv = si[nn * 9 + ai];
                    #pragma unroll
                    for (int ao = 0; ao < 8; ao++)
                        acc[ao] += iv * sw[(ao * 8 + ai) * 27 + wo];
                }
            }
        }
    }
    #pragma unroll
    for (int ao = 0; ao < 8; ao++)
        outp[(size_t)b * 4096 + t * 8 + ao] = qgelu_f(acc[ao]);
}

// ---------------------------------------------------------------------------
// Convpass up: xbuf[row][c] += pa[row,:] @ uw[:,c] + ub[c]
// ---------------------------------------------------------------------------
__global__ __launch_bounds__(256) void k_up(
    const float* __restrict__ pa, const float* __restrict__ uw,
    const float* __restrict__ ub, float* __restrict__ xbuf)
{
    __shared__ float s[8];
    int row = blockIdx.x, t = threadIdx.x;
    if (t < 8) s[t] = pa[(size_t)row * kAD + t];
    __syncthreads();
    #pragma unroll
    for (int rep = 0; rep < 2; rep++) {
        int c = t + rep * 256;
        float acc = ub[c];
        #pragma unroll
        for (int a = 0; a < 8; a++) acc += s[a] * uw[a * kC + c];
        xbuf[(size_t)row * kC + c] += acc;
    }
}

// ---------------------------------------------------------------------------
extern "C" void kernel_launch(void* const* d_in, const int* in_sizes, int n_in,
                              void* d_out, int out_size, void* d_ws, size_t ws_size,
                              hipStream_t stream)
{
    const float* x     = (const float*)d_in[0];
    const float* pos   = (const float*)d_in[1];
    const float* ln1g  = (const float*)d_in[2];
    const float* ln1b  = (const float*)d_in[3];
    const float* qkvw  = (const float*)d_in[4];
    const float* projw = (const float*)d_in[5];
    const float* projb = (const float*)d_in[6];
    const float* dw1   = (const float*)d_in[7];
    const float* db1   = (const float*)d_in[8];
    const float* cw1   = (const float*)d_in[9];
    const float* cb1   = (const float*)d_in[10];
    const float* uw1   = (const float*)d_in[11];
    const float* ub1   = (const float*)d_in[12];
    const float* ln2g  = (const float*)d_in[13];
    const float* ln2b  = (const float*)d_in[14];
    const float* fw1   = (const float*)d_in[15];
    const float* fb1   = (const float*)d_in[16];
    const float* fw2   = (const float*)d_in[17];
    const float* fb2   = (const float*)d_in[18];
    const float* dw2   = (const float*)d_in[19];
    const float* db2   = (const float*)d_in[20];
    const float* cw2   = (const float*)d_in[21];
    const float* cb2   = (const float*)d_in[22];
    const float* uw2   = (const float*)d_in[23];
    const float* ub2   = (const float*)d_in[24];
    float* out = (float*)d_out;

    // workspace layout (bytes):
    //   0         xbuf  f32  [16384][512]   33,554,432
    //   33554432  hb    bf16 [16384][512]   16,777,216
    //   50331648  obuf  bf16 [16384][512]   16,777,216   } midb aliases these
    //   67108864  qkvb  bf16 [256bh][3][512][64] 50,331,648 } two (67.1 MB)
    //   117440512 qkvT/projT/fw1T/fw2T bf16  10,485,760
    //   127926272 cpa f32, 128450560 cpb f32 -> end ~129 MB
    char* wsb = (char*)d_ws;
    float*  xbuf = (float*)wsb;
    bf16_t* hb   = (bf16_t*)(wsb + 33554432);
    bf16_t* obuf = (bf16_t*)(wsb + 50331648);
    bf16_t* qkvb = (bf16_t*)(wsb + 67108864);
    bf16_t* midb = (bf16_t*)(wsb + 50331648);   // stage-3 alias of obuf+qkvb
    bf16_t* qkvT = (bf16_t*)(wsb + 117440512);  // [1536][512]
    bf16_t* projT= (bf16_t*)(wsb + 119013376);  // [512][512]
    bf16_t* fw1T = (bf16_t*)(wsb + 119537664);  // [4096][512]
    bf16_t* fw2T = (bf16_t*)(wsb + 123731968);  // [512][4096]
    float*  cpa  = (float*)(wsb + 127926272);
    float*  cpb  = (float*)(wsb + 128450560);

    // weight transposes (fp32 -> bf16 B^T form)
    k_transpose<<<dim3(48, 16), 256, 0, stream>>>(qkvw, qkvT, 512, 1536);
    k_transpose<<<dim3(16, 16), 256, 0, stream>>>(projw, projT, 512, 512);
    k_transpose<<<dim3(128, 16), 256, 0, stream>>>(fw1, fw1T, 512, 4096);
    k_transpose<<<dim3(16, 128), 256, 0, stream>>>(fw2, fw2T, 4096, 512);

    // stage 1: xbuf = x + pos; hb = LN1(xbuf)
    k_addln<<<kBN, 256, 0, stream>>>(x, pos, ln1g, ln1b, xbuf, hb);

    // QKV -> blocked bf16 layout, flash attention, proj (+bias +residual)
    k_gemm<0, false, false, 2><<<dim3(12, 128), 256, 0, stream>>>(
        hb, qkvT, nullptr, nullptr, qkvb, kBN, 512, 1536);
    k_attn<<<kB * kH * 4, 256, 0, stream>>>(qkvb, obuf);
    k_gemm<0, true, true, 0><<<dim3(4, 128), 256, 0, stream>>>(
        obuf, projT, projb, xbuf, xbuf, kBN, 512, 512);

    // convpass 1 (on hb), accumulate into xbuf
    k_down<<<kBN * kAD / 256, 256, 0, stream>>>(hb, dw1, db1, cpa);
    k_conv<<<kB, 512, 0, stream>>>(cpa, cw1, cb1, cpb);
    k_up<<<kBN, 256, 0, stream>>>(cpb, uw1, ub1, xbuf);

    // stage 2: hb = LN2(xbuf)
    k_addln<<<kBN, 256, 0, stream>>>(xbuf, nullptr, ln2g, ln2b, nullptr, hb);

    // convpass 2, accumulate into xbuf
    k_down<<<kBN * kAD / 256, 256, 0, stream>>>(hb, dw2, db2, cpa);
    k_conv<<<kB, 512, 0, stream>>>(cpa, cw2, cb2, cpb);
    k_up<<<kBN, 256, 0, stream>>>(cpb, uw2, ub2, xbuf);

    // FFN in 2 row-chunks of 8192; gemm2 fuses bias+residual, writes d_out
    for (int ci = 0; ci < 2; ci++) {
        const bf16_t* hF = hb + (size_t)ci * 8192 * 512;
        k_gemm<2, true, false, 1><<<dim3(32, 64), 256, 0, stream>>>(
            hF, fw1T, fb1, nullptr, midb, 8192, 512, 4096);
        k_gemm<0, true, true, 0><<<dim3(4, 64), 256, 0, stream>>>(
            midb, fw2T, fb2,
            xbuf + (size_t)ci * 8192 * 512, out + (size_t)ci * 8192 * 512,
            8192, 4096, 512);
    }
}

// Round 3
// 744.943 us; speedup vs baseline: 6.3151x; 1.0024x over previous
//
#include <hip/hip_runtime.h>
#include <math.h>

typedef __bf16 bf16_t;
typedef __bf16 bf16x8 __attribute__((ext_vector_type(8)));
typedef float f32x4 __attribute__((ext_vector_type(4)));

constexpr int kB   = 32;
constexpr int kN   = 512;
constexpr int kC   = 512;
constexpr int kH   = 8;
constexpr int kAD  = 8;
constexpr int kMLP = 4096;
constexpr int kBN  = kB * kN;          // 16384 rows
constexpr float kEPS   = 1e-5f;
constexpr float kSCALE = 0.125f;       // DH^-0.5

__device__ __forceinline__ float qgelu_f(float x) {
    return x / (1.f + __expf(-1.702f * x));
}
__device__ __forceinline__ float gelu_f(float x) {
    return 0.5f * x * (1.f + erff(x * 0.70710678118654752f));
}

// async global->LDS, 16 bytes per lane. LDS dest must be uniform-base+lane*16.
__device__ __forceinline__ void gld_lds16(const void* g, void* l) {
    typedef const __attribute__((address_space(1))) unsigned int* gp_t;
    typedef __attribute__((address_space(3))) unsigned int* lp_t;
    __builtin_amdgcn_global_load_lds((gp_t)(unsigned long long)g,
                                     (lp_t)(unsigned)(unsigned long long)l,
                                     16, 0, 0);
}

// ---------------------------------------------------------------------------
// residual add (optional) + LayerNorm -> fp32 xout (optional) + bf16 hout
// ---------------------------------------------------------------------------
__global__ __launch_bounds__(256) void k_addln(
    const float* __restrict__ x, const float* __restrict__ pos,
    const float* __restrict__ g, const float* __restrict__ be,
    float* __restrict__ xout, bf16_t* __restrict__ hout)
{
    int row = blockIdx.x, tid = threadIdx.x;
    size_t base = (size_t)row * kC;
    float v0 = x[base + tid], v1 = x[base + tid + 256];
    if (pos) { v0 += pos[base + tid]; v1 += pos[base + tid + 256]; }
    if (xout) { xout[base + tid] = v0; xout[base + tid + 256] = v1; }
    float s = v0 + v1, q = v0 * v0 + v1 * v1;
    #pragma unroll
    for (int o = 32; o > 0; o >>= 1) {
        s += __shfl_down(s, o);
        q += __shfl_down(q, o);
    }
    __shared__ float ss[4], sq[4], mrs[2];
    int wv = tid >> 6, ln = tid & 63;
    if (!ln) { ss[wv] = s; sq[wv] = q; }
    __syncthreads();
    if (!tid) {
        float ts = ss[0] + ss[1] + ss[2] + ss[3];
        float tq = sq[0] + sq[1] + sq[2] + sq[3];
        float m = ts * (1.f / kC);
        float var = tq * (1.f / kC) - m * m;
        mrs[0] = m; mrs[1] = rsqrtf(var + kEPS);
    }
    __syncthreads();
    float m = mrs[0], r = mrs[1];
    hout[base + tid]       = (bf16_t)((v0 - m) * r * g[tid] + be[tid]);
    hout[base + tid + 256] = (bf16_t)((v1 - m) * r * g[tid + 256] + be[tid + 256]);
}

// ---------------------------------------------------------------------------
// fp32 [K][N] weight -> bf16 [N][K] transposed copy
// ---------------------------------------------------------------------------
__global__ __launch_bounds__(256) void k_transpose(
    const float* __restrict__ w, bf16_t* __restrict__ wt, int K, int N)
{
    __shared__ float t[32][33];
    int n0 = blockIdx.x * 32, k0 = blockIdx.y * 32;
    int tx = threadIdx.x & 31, ty = threadIdx.x >> 5;   // 32 x 8
    #pragma unroll
    for (int j = 0; j < 32; j += 8)
        t[ty + j][tx] = w[(size_t)(k0 + ty + j) * N + n0 + tx];
    __syncthreads();
    #pragma unroll
    for (int j = 0; j < 32; j += 8)
        wt[(size_t)(n0 + ty + j) * K + k0 + tx] = (bf16_t)t[tx][ty + j];
}

// ---------------------------------------------------------------------------
// bf16 MFMA GEMM (m97 structure): C = [res +] act(A[M,K] @ Bt[N,K]^T [+ bias])
// 128x128 tile, BK=32, 256 threads = 4 waves, wave = 64x64 (4x4 MFMA tiles).
// OMODE: 0 = fp32 out, 1 = bf16 out, 2 = bf16 scatter to qkv blocked layout.
// ---------------------------------------------------------------------------
template <int ACT, bool HASB, bool HASR, int OMODE>
__global__ __launch_bounds__(256) void k_gemm(
    const bf16_t* __restrict__ A, const bf16_t* __restrict__ Bt,
    const float* __restrict__ bias, const float* __restrict__ res,
    void* __restrict__ outv, int M, int K, int Nc)
{
    __shared__ bf16_t As[128 * 32];
    __shared__ bf16_t Bs[128 * 32];
    int tid = threadIdx.x;
    int col0 = blockIdx.x * 128, row0 = blockIdx.y * 128;
    int w = tid >> 6, l = tid & 63;
    int rw0 = (w & 1) * 64, cw0 = (w >> 1) * 64;
    int lr = tid >> 2, lc = (tid & 3) * 8;

    f32x4 acc[4][4];
    #pragma unroll
    for (int i = 0; i < 4; i++)
        #pragma unroll
        for (int j = 0; j < 4; j++)
            acc[i][j] = (f32x4){0.f, 0.f, 0.f, 0.f};

    const bf16_t* Ag  = A  + (size_t)(row0 + lr) * K + lc;
    const bf16_t* Ag2 = A  + (size_t)(row0 + 64 + lr) * K + lc;
    const bf16_t* Bg  = Bt + (size_t)(col0 + lr) * K + lc;
    const bf16_t* Bg2 = Bt + (size_t)(col0 + 64 + lr) * K + lc;
    bf16_t* Asd  = &As[tid * 8];
    bf16_t* Asd2 = &As[2048 + tid * 8];
    bf16_t* Bsd  = &Bs[tid * 8];
    bf16_t* Bsd2 = &Bs[2048 + tid * 8];

    int am = rw0 + (l & 15);
    int bn = cw0 + (l & 15);
    int kq = (l >> 4) * 8;

    for (int k0 = 0; k0 < K; k0 += 32) {
        gld_lds16(Ag + k0, Asd);
        gld_lds16(Ag2 + k0, Asd2);
        gld_lds16(Bg + k0, Bsd);
        gld_lds16(Bg2 + k0, Bsd2);
        __syncthreads();
        bf16x8 af[4], bfr[4];
        #pragma unroll
        for (int mt = 0; mt < 4; mt++)
            af[mt] = *(const bf16x8*)&As[(am + mt * 16) * 32 + kq];
        #pragma unroll
        for (int nt = 0; nt < 4; nt++)
            bfr[nt] = *(const bf16x8*)&Bs[(bn + nt * 16) * 32 + kq];
        #pragma unroll
        for (int mt = 0; mt < 4; mt++)
            #pragma unroll
            for (int nt = 0; nt < 4; nt++)
                acc[mt][nt] = __builtin_amdgcn_mfma_f32_16x16x32_bf16(
                    af[mt], bfr[nt], acc[mt][nt], 0, 0, 0);
        __syncthreads();
    }

    #pragma unroll
    for (int mt = 0; mt < 4; mt++) {
        int rowb = row0 + rw0 + mt * 16 + (l >> 4) * 4;
        #pragma unroll
        for (int nt = 0; nt < 4; nt++) {
            int col = col0 + cw0 + nt * 16 + (l & 15);
            float bv = HASB ? bias[col] : 0.f;
            #pragma unroll
            for (int p = 0; p < 4; p++) {
                float v = acc[mt][nt][p] + bv;
                if (ACT == 1) v = qgelu_f(v);
                if (ACT == 2) v = gelu_f(v);
                int r = rowb + p;
                if (OMODE == 0) {
                    if (HASR) v += res[(size_t)r * Nc + col];
                    ((float*)outv)[(size_t)r * Nc + col] = v;
                } else if (OMODE == 1) {
                    ((bf16_t*)outv)[(size_t)r * Nc + col] = (bf16_t)v;
                } else {
                    int bb = r >> 9, n = r & 511;
                    int which = col >> 9, hd = (col >> 6) & 7, d = col & 63;
                    ((bf16_t*)outv)[(((size_t)(bb * 8 + hd) * 3 + which) << 15)
                                    + n * 64 + d] = (bf16_t)v;
                }
            }
        }
    }
}

// ---------------------------------------------------------------------------
// In-block split-K bf16 MFMA GEMM for low-tile-count shapes (N=512).
// 1024 threads = 16 waves = 4 output quadrants x 4 K-groups. BK=128 staged
// as [4 kg][128 rows][32 k] (64 KB LDS); 3-round LDS reduce of partials.
// fp32 out, optional bias/res/act. Requires K % 128 == 0.
// ---------------------------------------------------------------------------
template <int ACT, bool HASB, bool HASR>
__global__ __launch_bounds__(1024, 4) void k_gemm_sk(
    const bf16_t* __restrict__ A, const bf16_t* __restrict__ Bt,
    const float* __restrict__ bias, const float* __restrict__ res,
    float* __restrict__ outp, int M, int K, int Nc)
{
    __shared__ char smemc[131072];
    bf16_t* As = (bf16_t*)smemc;            // [4][128][32] = 16384 elems
    bf16_t* Bs = (bf16_t*)(smemc + 65536);
    float*  R  = (float*)smemc;             // 16384 floats (reduction reuse)

    int tid = threadIdx.x;
    int col0 = blockIdx.x * 128, row0 = blockIdx.y * 128;
    int w = tid >> 6, l = tid & 63;
    int og = w & 3, kg = w >> 2;
    int rw0 = (og & 1) * 64, cw0 = (og >> 1) * 64;

    // staging decomposition: flat LDS elem f = round*8192 + tid*8
    //   kg2 = f>>12, r = (f>>5)&127, kc = f&31
    int sr  = (tid >> 2) & 127;
    int skc = (tid & 3) * 8;
    int kg0 = tid >> 9;                     // round0 kg2; round1 kg2 = kg0+2
    const bf16_t* Ag0 = A  + (size_t)(row0 + sr) * K + kg0 * 32 + skc;
    const bf16_t* Ag1 = A  + (size_t)(row0 + sr) * K + (kg0 + 2) * 32 + skc;
    const bf16_t* Bg0 = Bt + (size_t)(col0 + sr) * K + kg0 * 32 + skc;
    const bf16_t* Bg1 = Bt + (size_t)(col0 + sr) * K + (kg0 + 2) * 32 + skc;
    bf16_t* Asd0 = &As[tid * 8];
    bf16_t* Asd1 = &As[8192 + tid * 8];
    bf16_t* Bsd0 = &Bs[tid * 8];
    bf16_t* Bsd1 = &Bs[8192 + tid * 8];

    int am = rw0 + (l & 15);
    int bn = cw0 + (l & 15);
    int kq = kg * 4096 + (l >> 4) * 8;

    f32x4 acc[4][4];
    #pragma unroll
    for (int i = 0; i < 4; i++)
        #pragma unroll
        for (int j = 0; j < 4; j++)
            acc[i][j] = (f32x4){0.f, 0.f, 0.f, 0.f};

    for (int k0 = 0; k0 < K; k0 += 128) {
        gld_lds16(Ag0 + k0, Asd0);
        gld_lds16(Ag1 + k0, Asd1);
        gld_lds16(Bg0 + k0, Bsd0);
        gld_lds16(Bg1 + k0, Bsd1);
        __syncthreads();
        bf16x8 af[4], bfr;
        #pragma unroll
        for (int mt = 0; mt < 4; mt++)
            af[mt] = *(const bf16x8*)&As[(am + mt * 16) * 32 + kq];
        #pragma unroll
        for (int nt = 0; nt < 4; nt++) {
            bfr = *(const bf16x8*)&Bs[(bn + nt * 16) * 32 + kq];
            #pragma unroll
            for (int mt = 0; mt < 4; mt++)
                acc[mt][nt] = __builtin_amdgcn_mfma_f32_16x16x32_bf16(
                    af[mt], bfr, acc[mt][nt], 0, 0, 0);
        }
        __syncthreads();
    }

    // reduce K-group partials (kg 1..3) into kg 0's accumulators
    #pragma unroll
    for (int s = 1; s < 4; s++) {
        if (kg == s) {
            #pragma unroll
            for (int mt = 0; mt < 4; mt++)
                #pragma unroll
                for (int nt = 0; nt < 4; nt++)
                    *(f32x4*)&R[og * 4096 + (mt * 4 + nt) * 256 + l * 4] =
                        acc[mt][nt];
        }
        __syncthreads();
        if (kg == 0) {
            #pragma unroll
            for (int mt = 0; mt < 4; mt++)
                #pragma unroll
                for (int nt = 0; nt < 4; nt++)
                    acc[mt][nt] += *(const f32x4*)&R[og * 4096
                                                     + (mt * 4 + nt) * 256 + l * 4];
        }
        __syncthreads();
    }

    if (kg != 0) return;
    #pragma unroll
    for (int mt = 0; mt < 4; mt++) {
        int rowb = row0 + rw0 + mt * 16 + (l >> 4) * 4;
        #pragma unroll
        for (int nt = 0; nt < 4; nt++) {
            int col = col0 + cw0 + nt * 16 + (l & 15);
            float bv = HASB ? bias[col] : 0.f;
            #pragma unroll
            for (int p = 0; p < 4; p++) {
                float v = acc[mt][nt][p] + bv;
                if (ACT == 1) v = qgelu_f(v);
                if (ACT == 2) v = gelu_f(v);
                int r = rowb + p;
                if (HASR) v += res[(size_t)r * Nc + col];
                outp[(size_t)r * Nc + col] = v;
            }
        }
    }
}

// ---------------------------------------------------------------------------
// MFMA flash attention. qkvb layout: [(b*8+h)*3 + {q,k,v}][n][64] bf16.
// ---------------------------------------------------------------------------
__global__ __launch_bounds__(256) void k_attn(
    const bf16_t* __restrict__ qkvb, bf16_t* __restrict__ obuf)
{
    __shared__ bf16_t Ks[64 * 72];
    __shared__ bf16_t Vt[64 * 72];
    __shared__ bf16_t Ps[4][32 * 72];
    int bid = blockIdx.x;
    int qb = bid & 3, h = (bid >> 2) & 7, b = bid >> 5;
    int t = threadIdx.x, w = t >> 6, l = t & 63;
    const bf16_t* qp = qkvb + (((size_t)(b * 8 + h) * 3) << 15);
    const bf16_t* kp = qp + (1 << 15);
    const bf16_t* vp = qp + (2 << 15);
    int q0 = qb * 128 + w * 32;
    int l15 = l & 15, lq = (l >> 4) * 8;

    bf16x8 aq[2][2];
    #pragma unroll
    for (int mt = 0; mt < 2; mt++)
        #pragma unroll
        for (int kh = 0; kh < 2; kh++)
            aq[mt][kh] = *(const bf16x8*)(qp + (size_t)(q0 + mt * 16 + l15) * 64
                                          + kh * 32 + lq);

    f32x4 o[2][4];
    float m_run[2][4], l_run[2][4];
    #pragma unroll
    for (int mt = 0; mt < 2; mt++) {
        #pragma unroll
        for (int dt = 0; dt < 4; dt++) o[mt][dt] = (f32x4){0.f, 0.f, 0.f, 0.f};
        #pragma unroll
        for (int p = 0; p < 4; p++) { m_run[mt][p] = -1e30f; l_run[mt][p] = 0.f; }
    }

    int sr = t >> 2, scc = (t & 3) * 16;
    for (int kt = 0; kt < 8; kt++) {
        if (kt) __syncthreads();
        {
            const bf16_t* ks = kp + (size_t)(kt * 64 + sr) * 64 + scc;
            *(uint4*)&Ks[sr * 72 + scc]     = *(const uint4*)ks;
            *(uint4*)&Ks[sr * 72 + scc + 8] = *(const uint4*)(ks + 8);
            const bf16_t* vs = vp + (size_t)(kt * 64 + sr) * 64 + scc;
            bf16x8 v0 = *(const bf16x8*)vs;
            bf16x8 v1 = *(const bf16x8*)(vs + 8);
            #pragma unroll
            for (int e = 0; e < 8; e++) {
                Vt[(scc + e) * 72 + sr]     = v0[e];
                Vt[(scc + 8 + e) * 72 + sr] = v1[e];
            }
        }
        __syncthreads();
        #pragma unroll
        for (int mt = 0; mt < 2; mt++) {
            f32x4 sc[4];
            #pragma unroll
            for (int nt = 0; nt < 4; nt++) sc[nt] = (f32x4){0.f, 0.f, 0.f, 0.f};
            #pragma unroll
            for (int nt = 0; nt < 4; nt++)
                #pragma unroll
                for (int kh = 0; kh < 2; kh++) {
                    bf16x8 bk = *(const bf16x8*)&Ks[(nt * 16 + l15) * 72
                                                    + kh * 32 + lq];
                    sc[nt] = __builtin_amdgcn_mfma_f32_16x16x32_bf16(
                        aq[mt][kh], bk, sc[nt], 0, 0, 0);
                }
            #pragma unroll
            for (int nt = 0; nt < 4; nt++)
                #pragma unroll
                for (int p = 0; p < 4; p++) sc[nt][p] *= kSCALE;

            float mx[4], alpha[4], rs[4];
            #pragma unroll
            for (int p = 0; p < 4; p++) {
                float m4 = fmaxf(fmaxf(sc[0][p], sc[1][p]),
                                 fmaxf(sc[2][p], sc[3][p]));
                #pragma unroll
                for (int off = 1; off < 16; off <<= 1)
                    m4 = fmaxf(m4, __shfl_xor(m4, off));
                float mn = fmaxf(m_run[mt][p], m4);
                alpha[p] = __expf(m_run[mt][p] - mn);
                m_run[mt][p] = mn;
                mx[p] = mn;
                rs[p] = 0.f;
            }
            int prow = mt * 16 + (l >> 4) * 4;
            #pragma unroll
            for (int nt = 0; nt < 4; nt++)
                #pragma unroll
                for (int p = 0; p < 4; p++) {
                    float pv = __expf(sc[nt][p] - mx[p]);
                    rs[p] += pv;
                    Ps[w][(prow + p) * 72 + nt * 16 + l15] = (bf16_t)pv;
                }
            #pragma unroll
            for (int p = 0; p < 4; p++) {
                float r = rs[p];
                #pragma unroll
                for (int off = 1; off < 16; off <<= 1)
                    r += __shfl_xor(r, off);
                l_run[mt][p] = l_run[mt][p] * alpha[p] + r;
                #pragma unroll
                for (int dt = 0; dt < 4; dt++) o[mt][dt][p] *= alpha[p];
            }
            bf16x8 ap[2];
            #pragma unroll
            for (int kh = 0; kh < 2; kh++)
                ap[kh] = *(const bf16x8*)&Ps[w][(mt * 16 + l15) * 72
                                                + kh * 32 + lq];
            #pragma unroll
            for (int dt = 0; dt < 4; dt++)
                #pragma unroll
                for (int kh = 0; kh < 2; kh++) {
                    bf16x8 bv = *(const bf16x8*)&Vt[(dt * 16 + l15) * 72
                                                    + kh * 32 + lq];
                    o[mt][dt] = __builtin_amdgcn_mfma_f32_16x16x32_bf16(
                        ap[kh], bv, o[mt][dt], 0, 0, 0);
                }
        }
    }
    #pragma unroll
    for (int mt = 0; mt < 2; mt++)
        #pragma unroll
        for (int dt = 0; dt < 4; dt++)
            #pragma unroll
            for (int p = 0; p < 4; p++) {
                int q = q0 + mt * 16 + (l >> 4) * 4 + p;
                int col = h * 64 + dt * 16 + l15;
                float v = o[mt][dt][p] / l_run[mt][p];
                obuf[((size_t)b * 512 + q) * 512 + col] = (bf16_t)v;
            }
}

// ---------------------------------------------------------------------------
// Convpass down (bf16 h): cpa[row][a] = qgelu(h[row,:] @ dw[:,a] + db[a])
// ---------------------------------------------------------------------------
__global__ __launch_bounds__(256) void k_down(
    const bf16_t* __restrict__ h, const float* __restrict__ dw,
    const float* __restrict__ db, float* __restrict__ outp)
{
    __shared__ float sdw[kC * kAD];
    int t = threadIdx.x;
    for (int i = t; i < kC * kAD; i += 256) sdw[i] = dw[i];
    __syncthreads();
    int gt = blockIdx.x * 256 + t;
    int row = gt >> 3, a = gt & 7;
    const bf16x8* hr = (const bf16x8*)(h + (size_t)row * kC);
    float acc = 0.f;
    for (int k8 = 0; k8 < kC / 8; k8++) {
        bf16x8 hv = hr[k8];
        #pragma unroll
        for (int e = 0; e < 8; e++)
            acc += (float)hv[e] * sdw[(k8 * 8 + e) * kAD + a];
    }
    outp[gt] = qgelu_f(acc + db[a]);
}

// ---------------------------------------------------------------------------
// 3x3x3 SAME conv over 8x8x8, 8->8 ch, + bias, qgelu
// ---------------------------------------------------------------------------
__global__ __launch_bounds__(512) void k_conv(
    const float* __restrict__ inp, const float* __restrict__ cw,
    const float* __restrict__ cb, float* __restrict__ outp)
{
    __shared__ float si[512 * 9];
    __shared__ float sw[8 * 8 * 27];
    int b = blockIdx.x, t = threadIdx.x;
    for (int i = t; i < 512 * 8; i += 512) {
        int n = i >> 3, a = i & 7;
        si[n * 9 + a] = inp[(size_t)b * 4096 + i];
    }
    for (int i = t; i < 1728; i += 512) sw[i] = cw[i];
    __syncthreads();
    int z = t >> 6, y = (t >> 3) & 7, xx = t & 7;
    float acc[8];
    #pragma unroll
    for (int ao = 0; ao < 8; ao++) acc[ao] = cb[ao];
    for (int dz = -1; dz <= 1; dz++) {
        int zz = z + dz; if ((unsigned)zz > 7u) continue;
        for (int dy = -1; dy <= 1; dy++) {
            int yy = y + dy; if ((unsigned)yy > 7u) continue;
            for (int dx = -1; dx <= 1; dx++) {
                int xn = xx + dx; if ((unsigned)xn > 7u) continue;
                int nn = zz * 64 + yy * 8 + xn;
                int wo = ((dz + 1) * 3 + (dy + 1)) * 3 + (dx + 1);
                #pragma unroll
                for (int ai = 0; ai < 8; ai++) {
                    float iv = si[nn * 9 + ai];
                    #pragma unroll
                    for (int ao = 0; ao < 8; ao++)
                        acc[ao] += iv * sw[(ao * 8 + ai) * 27 + wo];
                }
            }
        }
    }
    #pragma unroll
    for (int ao = 0; ao < 8; ao++)
        outp[(size_t)b * 4096 + t * 8 + ao] = qgelu_f(acc[ao]);
}

// ---------------------------------------------------------------------------
// Convpass up: xbuf[row][c] += pa[row,:] @ uw[:,c] + ub[c]
// ---------------------------------------------------------------------------
__global__ __launch_bounds__(256) void k_up(
    const float* __restrict__ pa, const float* __restrict__ uw,
    const float* __restrict__ ub, float* __restrict__ xbuf)
{
    __shared__ float s[8];
    int row = blockIdx.x, t = threadIdx.x;
    if (t < 8) s[t] = pa[(size_t)row * kAD + t];
    __syncthreads();
    #pragma unroll
    for (int rep = 0; rep < 2; rep++) {
        int c = t + rep * 256;
        float acc = ub[c];
        #pragma unroll
        for (int a = 0; a < 8; a++) acc += s[a] * uw[a * kC + c];
        xbuf[(size_t)row * kC + c] += acc;
    }
}

// ---------------------------------------------------------------------------
extern "C" void kernel_launch(void* const* d_in, const int* in_sizes, int n_in,
                              void* d_out, int out_size, void* d_ws, size_t ws_size,
                              hipStream_t stream)
{
    const float* x     = (const float*)d_in[0];
    const float* pos   = (const float*)d_in[1];
    const float* ln1g  = (const float*)d_in[2];
    const float* ln1b  = (const float*)d_in[3];
    const float* qkvw  = (const float*)d_in[4];
    const float* projw = (const float*)d_in[5];
    const float* projb = (const float*)d_in[6];
    const float* dw1   = (const float*)d_in[7];
    const float* db1   = (const float*)d_in[8];
    const float* cw1   = (const float*)d_in[9];
    const float* cb1   = (const float*)d_in[10];
    const float* uw1   = (const float*)d_in[11];
    const float* ub1   = (const float*)d_in[12];
    const float* ln2g  = (const float*)d_in[13];
    const float* ln2b  = (const float*)d_in[14];
    const float* fw1   = (const float*)d_in[15];
    const float* fb1   = (const float*)d_in[16];
    const float* fw2   = (const float*)d_in[17];
    const float* fb2   = (const float*)d_in[18];
    const float* dw2   = (const float*)d_in[19];
    const float* db2   = (const float*)d_in[20];
    const float* cw2   = (const float*)d_in[21];
    const float* cb2   = (const float*)d_in[22];
    const float* uw2   = (const float*)d_in[23];
    const float* ub2   = (const float*)d_in[24];
    float* out = (float*)d_out;

    char* wsb = (char*)d_ws;
    float*  xbuf = (float*)wsb;
    bf16_t* hb   = (bf16_t*)(wsb + 33554432);
    bf16_t* obuf = (bf16_t*)(wsb + 50331648);
    bf16_t* qkvb = (bf16_t*)(wsb + 67108864);
    bf16_t* midb = (bf16_t*)(wsb + 50331648);   // stage-3 alias of obuf+qkvb
    bf16_t* qkvT = (bf16_t*)(wsb + 117440512);  // [1536][512]
    bf16_t* projT= (bf16_t*)(wsb + 119013376);  // [512][512]
    bf16_t* fw1T = (bf16_t*)(wsb + 119537664);  // [4096][512]
    bf16_t* fw2T = (bf16_t*)(wsb + 123731968);  // [512][4096]
    float*  cpa  = (float*)(wsb + 127926272);
    float*  cpb  = (float*)(wsb + 128450560);

    // weight transposes (fp32 -> bf16 B^T form)
    k_transpose<<<dim3(48, 16), 256, 0, stream>>>(qkvw, qkvT, 512, 1536);
    k_transpose<<<dim3(16, 16), 256, 0, stream>>>(projw, projT, 512, 512);
    k_transpose<<<dim3(128, 16), 256, 0, stream>>>(fw1, fw1T, 512, 4096);
    k_transpose<<<dim3(16, 128), 256, 0, stream>>>(fw2, fw2T, 4096, 512);

    // stage 1: xbuf = x + pos; hb = LN1(xbuf)
    k_addln<<<kBN, 256, 0, stream>>>(x, pos, ln1g, ln1b, xbuf, hb);

    // QKV -> blocked bf16 layout, flash attention, proj (+bias +residual)
    k_gemm<0, false, false, 2><<<dim3(12, 128), 256, 0, stream>>>(
        hb, qkvT, nullptr, nullptr, qkvb, kBN, 512, 1536);
    k_attn<<<kB * kH * 4, 256, 0, stream>>>(qkvb, obuf);
    k_gemm_sk<0, true, true><<<dim3(4, 128), 1024, 0, stream>>>(
        obuf, projT, projb, xbuf, xbuf, kBN, 512, 512);

    // convpass 1 (on hb), accumulate into xbuf
    k_down<<<kBN * kAD / 256, 256, 0, stream>>>(hb, dw1, db1, cpa);
    k_conv<<<kB, 512, 0, stream>>>(cpa, cw1, cb1, cpb);
    k_up<<<kBN, 256, 0, stream>>>(cpb, uw1, ub1, xbuf);

    // stage 2: hb = LN2(xbuf)
    k_addln<<<kBN, 256, 0, stream>>>(xbuf, nullptr, ln2g, ln2b, nullptr, hb);

    // convpass 2, accumulate into xbuf
    k_down<<<kBN * kAD / 256, 256, 0, stream>>>(hb, dw2, db2, cpa);
    k_conv<<<kB, 512, 0, stream>>>(cpa, cw2, cb2, cpb);
    k_up<<<kBN, 256, 0, stream>>>(cpb, uw2, ub2, xbuf);

    // FFN in 2 row-chunks of 8192; gemm2 (split-K) fuses bias+residual -> out
    for (int ci = 0; ci < 2; ci++) {
        const bf16_t* hF = hb + (size_t)ci * 8192 * 512;
        k_gemm<2, true, false, 1><<<dim3(32, 64), 256, 0, stream>>>(
            hF, fw1T, fb1, nullptr, midb, 8192, 512, 4096);
        k_gemm_sk<0, true, true><<<dim3(4, 64), 1024, 0, stream>>>(
            midb, fw2T, fb2,
            xbuf + (size_t)ci * 8192 * 512, out + (size_t)ci * 8192 * 512,
            8192, 4096, 512);
    }
}

// Round 4
// 710.203 us; speedup vs baseline: 6.6240x; 1.0489x over previous
//
#include <hip/hip_runtime.h>
#include <math.h>

typedef __bf16 bf16_t;
typedef __bf16 bf16x8 __attribute__((ext_vector_type(8)));
typedef float f32x4 __attribute__((ext_vector_type(4)));

constexpr int kB   = 32;
constexpr int kN   = 512;
constexpr int kC   = 512;
constexpr int kH   = 8;
constexpr int kAD  = 8;
constexpr int kMLP = 4096;
constexpr int kBN  = kB * kN;          // 16384 rows
constexpr float kEPS   = 1e-5f;
constexpr float kSCALE = 0.125f;       // DH^-0.5

__device__ __forceinline__ float qgelu_f(float x) {
    return x / (1.f + __expf(-1.702f * x));
}
__device__ __forceinline__ float gelu_f(float x) {
    return 0.5f * x * (1.f + erff(x * 0.70710678118654752f));
}

// async global->LDS, 16 bytes per lane. LDS dest must be uniform-base+lane*16.
__device__ __forceinline__ void gld_lds16(const void* g, void* l) {
    typedef const __attribute__((address_space(1))) unsigned int* gp_t;
    typedef __attribute__((address_space(3))) unsigned int* lp_t;
    __builtin_amdgcn_global_load_lds((gp_t)(unsigned long long)g,
                                     (lp_t)(unsigned)(unsigned long long)l,
                                     16, 0, 0);
}

// ---------------------------------------------------------------------------
// residual add (optional) + LayerNorm -> fp32 xout (optional) + bf16 hout
// ---------------------------------------------------------------------------
__global__ __launch_bounds__(256) void k_addln(
    const float* __restrict__ x, const float* __restrict__ pos,
    const float* __restrict__ g, const float* __restrict__ be,
    float* __restrict__ xout, bf16_t* __restrict__ hout)
{
    int row = blockIdx.x, tid = threadIdx.x;
    size_t base = (size_t)row * kC;
    float v0 = x[base + tid], v1 = x[base + tid + 256];
    if (pos) { v0 += pos[base + tid]; v1 += pos[base + tid + 256]; }
    if (xout) { xout[base + tid] = v0; xout[base + tid + 256] = v1; }
    float s = v0 + v1, q = v0 * v0 + v1 * v1;
    #pragma unroll
    for (int o = 32; o > 0; o >>= 1) {
        s += __shfl_down(s, o);
        q += __shfl_down(q, o);
    }
    __shared__ float ss[4], sq[4], mrs[2];
    int wv = tid >> 6, ln = tid & 63;
    if (!ln) { ss[wv] = s; sq[wv] = q; }
    __syncthreads();
    if (!tid) {
        float ts = ss[0] + ss[1] + ss[2] + ss[3];
        float tq = sq[0] + sq[1] + sq[2] + sq[3];
        float m = ts * (1.f / kC);
        float var = tq * (1.f / kC) - m * m;
        mrs[0] = m; mrs[1] = rsqrtf(var + kEPS);
    }
    __syncthreads();
    float m = mrs[0], r = mrs[1];
    hout[base + tid]       = (bf16_t)((v0 - m) * r * g[tid] + be[tid]);
    hout[base + tid + 256] = (bf16_t)((v1 - m) * r * g[tid + 256] + be[tid + 256]);
}

// ---------------------------------------------------------------------------
// fp32 [K][N] weight -> bf16 [N][K] transposed copy
// ---------------------------------------------------------------------------
__global__ __launch_bounds__(256) void k_transpose(
    const float* __restrict__ w, bf16_t* __restrict__ wt, int K, int N)
{
    __shared__ float t[32][33];
    int n0 = blockIdx.x * 32, k0 = blockIdx.y * 32;
    int tx = threadIdx.x & 31, ty = threadIdx.x >> 5;   // 32 x 8
    #pragma unroll
    for (int j = 0; j < 32; j += 8)
        t[ty + j][tx] = w[(size_t)(k0 + ty + j) * N + n0 + tx];
    __syncthreads();
    #pragma unroll
    for (int j = 0; j < 32; j += 8)
        wt[(size_t)(n0 + ty + j) * K + k0 + tx] = (bf16_t)t[tx][ty + j];
}

// ---------------------------------------------------------------------------
// bf16 MFMA GEMM (m97 structure): C = [res +] act(A[M,K] @ Bt[N,K]^T [+ bias])
// 128x128 tile, BK=32, 256 threads = 4 waves, wave = 64x64 (4x4 MFMA tiles).
// OMODE: 0 = fp32 out, 1 = bf16 out, 2 = bf16 scatter to qkv blocked layout.
// ---------------------------------------------------------------------------
template <int ACT, bool HASB, bool HASR, int OMODE>
__global__ __launch_bounds__(256) void k_gemm(
    const bf16_t* __restrict__ A, const bf16_t* __restrict__ Bt,
    const float* __restrict__ bias, const float* __restrict__ res,
    void* __restrict__ outv, int M, int K, int Nc)
{
    __shared__ bf16_t As[128 * 32];
    __shared__ bf16_t Bs[128 * 32];
    int tid = threadIdx.x;
    int col0 = blockIdx.x * 128, row0 = blockIdx.y * 128;
    int w = tid >> 6, l = tid & 63;
    int rw0 = (w & 1) * 64, cw0 = (w >> 1) * 64;
    int lr = tid >> 2, lc = (tid & 3) * 8;

    f32x4 acc[4][4];
    #pragma unroll
    for (int i = 0; i < 4; i++)
        #pragma unroll
        for (int j = 0; j < 4; j++)
            acc[i][j] = (f32x4){0.f, 0.f, 0.f, 0.f};

    const bf16_t* Ag  = A  + (size_t)(row0 + lr) * K + lc;
    const bf16_t* Ag2 = A  + (size_t)(row0 + 64 + lr) * K + lc;
    const bf16_t* Bg  = Bt + (size_t)(col0 + lr) * K + lc;
    const bf16_t* Bg2 = Bt + (size_t)(col0 + 64 + lr) * K + lc;
    bf16_t* Asd  = &As[tid * 8];
    bf16_t* Asd2 = &As[2048 + tid * 8];
    bf16_t* Bsd  = &Bs[tid * 8];
    bf16_t* Bsd2 = &Bs[2048 + tid * 8];

    int am = rw0 + (l & 15);
    int bn = cw0 + (l & 15);
    int kq = (l >> 4) * 8;

    for (int k0 = 0; k0 < K; k0 += 32) {
        gld_lds16(Ag + k0, Asd);
        gld_lds16(Ag2 + k0, Asd2);
        gld_lds16(Bg + k0, Bsd);
        gld_lds16(Bg2 + k0, Bsd2);
        __syncthreads();
        bf16x8 af[4], bfr[4];
        #pragma unroll
        for (int mt = 0; mt < 4; mt++)
            af[mt] = *(const bf16x8*)&As[(am + mt * 16) * 32 + kq];
        #pragma unroll
        for (int nt = 0; nt < 4; nt++)
            bfr[nt] = *(const bf16x8*)&Bs[(bn + nt * 16) * 32 + kq];
        #pragma unroll
        for (int mt = 0; mt < 4; mt++)
            #pragma unroll
            for (int nt = 0; nt < 4; nt++)
                acc[mt][nt] = __builtin_amdgcn_mfma_f32_16x16x32_bf16(
                    af[mt], bfr[nt], acc[mt][nt], 0, 0, 0);
        __syncthreads();
    }

    #pragma unroll
    for (int mt = 0; mt < 4; mt++) {
        int rowb = row0 + rw0 + mt * 16 + (l >> 4) * 4;
        #pragma unroll
        for (int nt = 0; nt < 4; nt++) {
            int col = col0 + cw0 + nt * 16 + (l & 15);
            float bv = HASB ? bias[col] : 0.f;
            #pragma unroll
            for (int p = 0; p < 4; p++) {
                float v = acc[mt][nt][p] + bv;
                if (ACT == 1) v = qgelu_f(v);
                if (ACT == 2) v = gelu_f(v);
                int r = rowb + p;
                if (OMODE == 0) {
                    if (HASR) v += res[(size_t)r * Nc + col];
                    ((float*)outv)[(size_t)r * Nc + col] = v;
                } else if (OMODE == 1) {
                    ((bf16_t*)outv)[(size_t)r * Nc + col] = (bf16_t)v;
                } else {
                    int bb = r >> 9, n = r & 511;
                    int which = col >> 9, hd = (col >> 6) & 7, d = col & 63;
                    ((bf16_t*)outv)[(((size_t)(bb * 8 + hd) * 3 + which) << 15)
                                    + n * 64 + d] = (bf16_t)v;
                }
            }
        }
    }
}

// ---------------------------------------------------------------------------
// 64x128-tile bf16 MFMA GEMM for N=512 shapes: high blocks/CU (grid 4 x M/64).
// 256 threads = 4 waves, wave tile 32x64 (2x4 MFMA tiles), BK=32, 12 KB LDS.
// Supports strided A (ldA) and strided/offset B (ldB) for K-chunked weights.
// fp32 output with optional bias/act/residual.
// ---------------------------------------------------------------------------
template <int ACT, bool HASB, bool HASR>
__global__ __launch_bounds__(256, 4) void k_gemm64(
    const bf16_t* __restrict__ A, const bf16_t* __restrict__ Bt,
    const float* __restrict__ bias, const float* __restrict__ res,
    float* __restrict__ outp, int M, int Kl, int ldA, int ldB, int Nc)
{
    __shared__ bf16_t As[64 * 32];      // 4 KB
    __shared__ bf16_t Bs[128 * 32];     // 8 KB
    int tid = threadIdx.x;
    int col0 = blockIdx.x * 128, row0 = blockIdx.y * 64;
    int w = tid >> 6, l = tid & 63;
    int rw0 = (w & 1) * 32, cw0 = (w >> 1) * 64;

    f32x4 acc[2][4];
    #pragma unroll
    for (int i = 0; i < 2; i++)
        #pragma unroll
        for (int j = 0; j < 4; j++)
            acc[i][j] = (f32x4){0.f, 0.f, 0.f, 0.f};

    int sr = tid >> 2, sc = (tid & 3) * 8;
    const bf16_t* Ag  = A  + (size_t)(row0 + sr) * ldA + sc;   // 64 rows
    const bf16_t* Bg0 = Bt + (size_t)(col0 + sr) * ldB + sc;
    const bf16_t* Bg1 = Bt + (size_t)(col0 + 64 + sr) * ldB + sc;
    bf16_t* Asd  = &As[tid * 8];
    bf16_t* Bsd0 = &Bs[tid * 8];
    bf16_t* Bsd1 = &Bs[2048 + tid * 8];

    int am = rw0 + (l & 15);
    int bn = cw0 + (l & 15);
    int kq = (l >> 4) * 8;

    for (int k0 = 0; k0 < Kl; k0 += 32) {
        gld_lds16(Ag + k0, Asd);
        gld_lds16(Bg0 + k0, Bsd0);
        gld_lds16(Bg1 + k0, Bsd1);
        __syncthreads();
        bf16x8 af[2], bfr[4];
        #pragma unroll
        for (int mt = 0; mt < 2; mt++)
            af[mt] = *(const bf16x8*)&As[(am + mt * 16) * 32 + kq];
        #pragma unroll
        for (int nt = 0; nt < 4; nt++)
            bfr[nt] = *(const bf16x8*)&Bs[(bn + nt * 16) * 32 + kq];
        #pragma unroll
        for (int mt = 0; mt < 2; mt++)
            #pragma unroll
            for (int nt = 0; nt < 4; nt++)
                acc[mt][nt] = __builtin_amdgcn_mfma_f32_16x16x32_bf16(
                    af[mt], bfr[nt], acc[mt][nt], 0, 0, 0);
        __syncthreads();
    }

    #pragma unroll
    for (int mt = 0; mt < 2; mt++) {
        int rowb = row0 + rw0 + mt * 16 + (l >> 4) * 4;
        #pragma unroll
        for (int nt = 0; nt < 4; nt++) {
            int col = col0 + cw0 + nt * 16 + (l & 15);
            float bv = HASB ? bias[col] : 0.f;
            #pragma unroll
            for (int p = 0; p < 4; p++) {
                float v = acc[mt][nt][p] + bv;
                if (ACT == 1) v = qgelu_f(v);
                if (ACT == 2) v = gelu_f(v);
                int r = rowb + p;
                if (HASR) v += res[(size_t)r * Nc + col];
                outp[(size_t)r * Nc + col] = v;
            }
        }
    }
}

// ---------------------------------------------------------------------------
// MFMA flash attention. qkvb layout: [(b*8+h)*3 + {q,k,v}][n][64] bf16.
// ---------------------------------------------------------------------------
__global__ __launch_bounds__(256) void k_attn(
    const bf16_t* __restrict__ qkvb, bf16_t* __restrict__ obuf)
{
    __shared__ bf16_t Ks[64 * 72];
    __shared__ bf16_t Vt[64 * 72];
    __shared__ bf16_t Ps[4][32 * 72];
    int bid = blockIdx.x;
    int qb = bid & 3, h = (bid >> 2) & 7, b = bid >> 5;
    int t = threadIdx.x, w = t >> 6, l = t & 63;
    const bf16_t* qp = qkvb + (((size_t)(b * 8 + h) * 3) << 15);
    const bf16_t* kp = qp + (1 << 15);
    const bf16_t* vp = qp + (2 << 15);
    int q0 = qb * 128 + w * 32;
    int l15 = l & 15, lq = (l >> 4) * 8;

    bf16x8 aq[2][2];
    #pragma unroll
    for (int mt = 0; mt < 2; mt++)
        #pragma unroll
        for (int kh = 0; kh < 2; kh++)
            aq[mt][kh] = *(const bf16x8*)(qp + (size_t)(q0 + mt * 16 + l15) * 64
                                          + kh * 32 + lq);

    f32x4 o[2][4];
    float m_run[2][4], l_run[2][4];
    #pragma unroll
    for (int mt = 0; mt < 2; mt++) {
        #pragma unroll
        for (int dt = 0; dt < 4; dt++) o[mt][dt] = (f32x4){0.f, 0.f, 0.f, 0.f};
        #pragma unroll
        for (int p = 0; p < 4; p++) { m_run[mt][p] = -1e30f; l_run[mt][p] = 0.f; }
    }

    int sr = t >> 2, scc = (t & 3) * 16;
    for (int kt = 0; kt < 8; kt++) {
        if (kt) __syncthreads();
        {
            const bf16_t* ks = kp + (size_t)(kt * 64 + sr) * 64 + scc;
            *(uint4*)&Ks[sr * 72 + scc]     = *(const uint4*)ks;
            *(uint4*)&Ks[sr * 72 + scc + 8] = *(const uint4*)(ks + 8);
            const bf16_t* vs = vp + (size_t)(kt * 64 + sr) * 64 + scc;
            bf16x8 v0 = *(const bf16x8*)vs;
            bf16x8 v1 = *(const bf16x8*)(vs + 8);
            #pragma unroll
            for (int e = 0; e < 8; e++) {
                Vt[(scc + e) * 72 + sr]     = v0[e];
                Vt[(scc + 8 + e) * 72 + sr] = v1[e];
            }
        }
        __syncthreads();
        #pragma unroll
        for (int mt = 0; mt < 2; mt++) {
            f32x4 sc[4];
            #pragma unroll
            for (int nt = 0; nt < 4; nt++) sc[nt] = (f32x4){0.f, 0.f, 0.f, 0.f};
            #pragma unroll
            for (int nt = 0; nt < 4; nt++)
                #pragma unroll
                for (int kh = 0; kh < 2; kh++) {
                    bf16x8 bk = *(const bf16x8*)&Ks[(nt * 16 + l15) * 72
                                                    + kh * 32 + lq];
                    sc[nt] = __builtin_amdgcn_mfma_f32_16x16x32_bf16(
                        aq[mt][kh], bk, sc[nt], 0, 0, 0);
                }
            #pragma unroll
            for (int nt = 0; nt < 4; nt++)
                #pragma unroll
                for (int p = 0; p < 4; p++) sc[nt][p] *= kSCALE;

            float mx[4], alpha[4], rs[4];
            #pragma unroll
            for (int p = 0; p < 4; p++) {
                float m4 = fmaxf(fmaxf(sc[0][p], sc[1][p]),
                                 fmaxf(sc[2][p], sc[3][p]));
                #pragma unroll
                for (int off = 1; off < 16; off <<= 1)
                    m4 = fmaxf(m4, __shfl_xor(m4, off));
                float mn = fmaxf(m_run[mt][p], m4);
                alpha[p] = __expf(m_run[mt][p] - mn);
                m_run[mt][p] = mn;
                mx[p] = mn;
                rs[p] = 0.f;
            }
            int prow = mt * 16 + (l >> 4) * 4;
            #pragma unroll
            for (int nt = 0; nt < 4; nt++)
                #pragma unroll
                for (int p = 0; p < 4; p++) {
                    float pv = __expf(sc[nt][p] - mx[p]);
                    rs[p] += pv;
                    Ps[w][(prow + p) * 72 + nt * 16 + l15] = (bf16_t)pv;
                }
            #pragma unroll
            for (int p = 0; p < 4; p++) {
                float r = rs[p];
                #pragma unroll
                for (int off = 1; off < 16; off <<= 1)
                    r += __shfl_xor(r, off);
                l_run[mt][p] = l_run[mt][p] * alpha[p] + r;
                #pragma unroll
                for (int dt = 0; dt < 4; dt++) o[mt][dt][p] *= alpha[p];
            }
            bf16x8 ap[2];
            #pragma unroll
            for (int kh = 0; kh < 2; kh++)
                ap[kh] = *(const bf16x8*)&Ps[w][(mt * 16 + l15) * 72
                                                + kh * 32 + lq];
            #pragma unroll
            for (int dt = 0; dt < 4; dt++)
                #pragma unroll
                for (int kh = 0; kh < 2; kh++) {
                    bf16x8 bv = *(const bf16x8*)&Vt[(dt * 16 + l15) * 72
                                                    + kh * 32 + lq];
                    o[mt][dt] = __builtin_amdgcn_mfma_f32_16x16x32_bf16(
                        ap[kh], bv, o[mt][dt], 0, 0, 0);
                }
        }
    }
    #pragma unroll
    for (int mt = 0; mt < 2; mt++)
        #pragma unroll
        for (int dt = 0; dt < 4; dt++)
            #pragma unroll
            for (int p = 0; p < 4; p++) {
                int q = q0 + mt * 16 + (l >> 4) * 4 + p;
                int col = h * 64 + dt * 16 + l15;
                float v = o[mt][dt][p] / l_run[mt][p];
                obuf[((size_t)b * 512 + q) * 512 + col] = (bf16_t)v;
            }
}

// ---------------------------------------------------------------------------
// Convpass down (bf16 h): cpa[row][a] = qgelu(h[row,:] @ dw[:,a] + db[a])
// ---------------------------------------------------------------------------
__global__ __launch_bounds__(256) void k_down(
    const bf16_t* __restrict__ h, const float* __restrict__ dw,
    const float* __restrict__ db, float* __restrict__ outp)
{
    __shared__ float sdw[kC * kAD];
    int t = threadIdx.x;
    for (int i = t; i < kC * kAD; i += 256) sdw[i] = dw[i];
    __syncthreads();
    int gt = blockIdx.x * 256 + t;
    int row = gt >> 3, a = gt & 7;
    const bf16x8* hr = (const bf16x8*)(h + (size_t)row * kC);
    float acc = 0.f;
    for (int k8 = 0; k8 < kC / 8; k8++) {
        bf16x8 hv = hr[k8];
        #pragma unroll
        for (int e = 0; e < 8; e++)
            acc += (float)hv[e] * sdw[(k8 * 8 + e) * kAD + a];
    }
    outp[gt] = qgelu_f(acc + db[a]);
}

// ---------------------------------------------------------------------------
// 3x3x3 SAME conv over 8x8x8, 8->8 ch, + bias, qgelu
// ---------------------------------------------------------------------------
__global__ __launch_bounds__(512) void k_conv(
    const float* __restrict__ inp, const float* __restrict__ cw,
    const float* __restrict__ cb, float* __restrict__ outp)
{
    __shared__ float si[512 * 9];
    __shared__ float sw[8 * 8 * 27];
    int b = blockIdx.x, t = threadIdx.x;
    for (int i = t; i < 512 * 8; i += 512) {
        int n = i >> 3, a = i & 7;
        si[n * 9 + a] = inp[(size_t)b * 4096 + i];
    }
    for (int i = t; i < 1728; i += 512) sw[i] = cw[i];
    __syncthreads();
    int z = t >> 6, y = (t >> 3) & 7, xx = t & 7;
    float acc[8];
    #pragma unroll
    for (int ao = 0; ao < 8; ao++) acc[ao] = cb[ao];
    for (int dz = -1; dz <= 1; dz++) {
        int zz = z + dz; if ((unsigned)zz > 7u) continue;
        for (int dy = -1; dy <= 1; dy++) {
            int yy = y + dy; if ((unsigned)yy > 7u) continue;
            for (int dx = -1; dx <= 1; dx++) {
                int xn = xx + dx; if ((unsigned)xn > 7u) continue;
                int nn = zz * 64 + yy * 8 + xn;
                int wo = ((dz + 1) * 3 + (dy + 1)) * 3 + (dx + 1);
                #pragma unroll
                for (int ai = 0; ai < 8; ai++) {
                    float iv = si[nn * 9 + ai];
                    #pragma unroll
                    for (int ao = 0; ao < 8; ao++)
                        acc[ao] += iv * sw[(ao * 8 + ai) * 27 + wo];
                }
            }
        }
    }
    #pragma unroll
    for (int ao = 0; ao < 8; ao++)
        outp[(size_t)b * 4096 + t * 8 + ao] = qgelu_f(acc[ao]);
}

// ---------------------------------------------------------------------------
// Convpass up: xbuf[row][c] += pa[row,:] @ uw[:,c] + ub[c]
// ---------------------------------------------------------------------------
__global__ __launch_bounds__(256) void k_up(
    const float* __restrict__ pa, const float* __restrict__ uw,
    const float* __restrict__ ub, float* __restrict__ xbuf)
{
    __shared__ float s[8];
    int row = blockIdx.x, t = threadIdx.x;
    if (t < 8) s[t] = pa[(size_t)row * kAD + t];
    __syncthreads();
    #pragma unroll
    for (int rep = 0; rep < 2; rep++) {
        int c = t + rep * 256;
        float acc = ub[c];
        #pragma unroll
        for (int a = 0; a < 8; a++) acc += s[a] * uw[a * kC + c];
        xbuf[(size_t)row * kC + c] += acc;
    }
}

// ---------------------------------------------------------------------------
extern "C" void kernel_launch(void* const* d_in, const int* in_sizes, int n_in,
                              void* d_out, int out_size, void* d_ws, size_t ws_size,
                              hipStream_t stream)
{
    const float* x     = (const float*)d_in[0];
    const float* pos   = (const float*)d_in[1];
    const float* ln1g  = (const float*)d_in[2];
    const float* ln1b  = (const float*)d_in[3];
    const float* qkvw  = (const float*)d_in[4];
    const float* projw = (const float*)d_in[5];
    const float* projb = (const float*)d_in[6];
    const float* dw1   = (const float*)d_in[7];
    const float* db1   = (const float*)d_in[8];
    const float* cw1   = (const float*)d_in[9];
    const float* cb1   = (const float*)d_in[10];
    const float* uw1   = (const float*)d_in[11];
    const float* ub1   = (const float*)d_in[12];
    const float* ln2g  = (const float*)d_in[13];
    const float* ln2b  = (const float*)d_in[14];
    const float* fw1   = (const float*)d_in[15];
    const float* fb1   = (const float*)d_in[16];
    const float* fw2   = (const float*)d_in[17];
    const float* fb2   = (const float*)d_in[18];
    const float* dw2   = (const float*)d_in[19];
    const float* db2   = (const float*)d_in[20];
    const float* cw2   = (const float*)d_in[21];
    const float* cb2   = (const float*)d_in[22];
    const float* uw2   = (const float*)d_in[23];
    const float* ub2   = (const float*)d_in[24];
    float* out = (float*)d_out;

    char* wsb = (char*)d_ws;
    float*  xbuf = (float*)wsb;
    bf16_t* hb   = (bf16_t*)(wsb + 33554432);
    bf16_t* obuf = (bf16_t*)(wsb + 50331648);
    bf16_t* qkvb = (bf16_t*)(wsb + 67108864);
    bf16_t* midb = (bf16_t*)(wsb + 50331648);   // stage-3 alias: [16384][2048]
    bf16_t* qkvT = (bf16_t*)(wsb + 117440512);  // [1536][512]
    bf16_t* projT= (bf16_t*)(wsb + 119013376);  // [512][512]
    bf16_t* fw1T = (bf16_t*)(wsb + 119537664);  // [4096][512]
    bf16_t* fw2T = (bf16_t*)(wsb + 123731968);  // [512][4096]
    float*  cpa  = (float*)(wsb + 127926272);
    float*  cpb  = (float*)(wsb + 128450560);

    // weight transposes (fp32 -> bf16 B^T form)
    k_transpose<<<dim3(48, 16), 256, 0, stream>>>(qkvw, qkvT, 512, 1536);
    k_transpose<<<dim3(16, 16), 256, 0, stream>>>(projw, projT, 512, 512);
    k_transpose<<<dim3(128, 16), 256, 0, stream>>>(fw1, fw1T, 512, 4096);
    k_transpose<<<dim3(16, 128), 256, 0, stream>>>(fw2, fw2T, 4096, 512);

    // stage 1: xbuf = x + pos; hb = LN1(xbuf)
    k_addln<<<kBN, 256, 0, stream>>>(x, pos, ln1g, ln1b, xbuf, hb);

    // QKV -> blocked bf16 layout, flash attention, proj (+bias +residual)
    k_gemm<0, false, false, 2><<<dim3(12, 128), 256, 0, stream>>>(
        hb, qkvT, nullptr, nullptr, qkvb, kBN, 512, 1536);
    k_attn<<<kB * kH * 4, 256, 0, stream>>>(qkvb, obuf);
    k_gemm64<0, true, true><<<dim3(4, 256), 256, 0, stream>>>(
        obuf, projT, projb, xbuf, xbuf, kBN, 512, 512, 512, 512);

    // convpass 1 (on hb), accumulate into xbuf
    k_down<<<kBN * kAD / 256, 256, 0, stream>>>(hb, dw1, db1, cpa);
    k_conv<<<kB, 512, 0, stream>>>(cpa, cw1, cb1, cpb);
    k_up<<<kBN, 256, 0, stream>>>(cpb, uw1, ub1, xbuf);

    // stage 2: hb = LN2(xbuf)
    k_addln<<<kBN, 256, 0, stream>>>(xbuf, nullptr, ln2g, ln2b, nullptr, hb);

    // convpass 2, accumulate into xbuf
    k_down<<<kBN * kAD / 256, 256, 0, stream>>>(hb, dw2, db2, cpa);
    k_conv<<<kB, 512, 0, stream>>>(cpa, cw2, cb2, cpb);
    k_up<<<kBN, 256, 0, stream>>>(cpb, uw2, ub2, xbuf);

    // FFN, K-chunked (2 x 2048 mid cols), full M=16384 per dispatch.
    // chunk 0: xbuf += mid0 @ fw2[0:2048]; chunk 1: out = xbuf + mid1 @ ... + fb2
    // FFN1 chunk: mid = gelu(hb @ fw1T[c*2048 ..][512]^T + fb1[c*2048..])
    k_gemm<2, true, false, 1><<<dim3(16, 128), 256, 0, stream>>>(
        hb, fw1T, fb1, nullptr, midb, kBN, 512, 2048);
    k_gemm64<0, false, true><<<dim3(4, 256), 256, 0, stream>>>(
        midb, fw2T, nullptr, xbuf, xbuf, kBN, 2048, 2048, 4096, 512);
    k_gemm<2, true, false, 1><<<dim3(16, 128), 256, 0, stream>>>(
        hb, fw1T + (size_t)2048 * 512, fb1 + 2048, nullptr, midb,
        kBN, 512, 2048);
    k_gemm64<0, true, true><<<dim3(4, 256), 256, 0, stream>>>(
        midb, fw2T + 2048, fb2, xbuf, out, kBN, 2048, 2048, 4096, 512);
}

// Round 5
// 669.259 us; speedup vs baseline: 7.0292x; 1.0612x over previous
//
#include <hip/hip_runtime.h>
#include <math.h>

typedef __bf16 bf16_t;
typedef __bf16 bf16x8 __attribute__((ext_vector_type(8)));
typedef float f32x4 __attribute__((ext_vector_type(4)));

constexpr int kB   = 32;
constexpr int kN   = 512;
constexpr int kC   = 512;
constexpr int kH   = 8;
constexpr int kAD  = 8;
constexpr int kMLP = 4096;
constexpr int kBN  = kB * kN;          // 16384 rows
constexpr float kEPS   = 1e-5f;
constexpr float kSCALE = 0.125f;       // DH^-0.5

__device__ __forceinline__ float qgelu_f(float x) {
    return x / (1.f + __expf(-1.702f * x));
}
// tanh-approx gelu: max |err| vs exact erf-gelu ~3e-4, well under threshold.
__device__ __forceinline__ float gelu_f(float x) {
    float u = 1.5957691216f * x * (1.f + 0.044715f * x * x);  // 2*0.79788456*(...)
    float e = __expf(u);
    float th = 1.f - 2.f / (e + 1.f);          // tanh(u/2*2)=tanh(0.797..*..)
    return 0.5f * x * (1.f + th);
}

// async global->LDS, 16 bytes per lane. LDS dest must be uniform-base+lane*16.
__device__ __forceinline__ void gld_lds16(const void* g, void* l) {
    typedef const __attribute__((address_space(1))) unsigned int* gp_t;
    typedef __attribute__((address_space(3))) unsigned int* lp_t;
    __builtin_amdgcn_global_load_lds((gp_t)(unsigned long long)g,
                                     (lp_t)(unsigned)(unsigned long long)l,
                                     16, 0, 0);
}

// ---------------------------------------------------------------------------
// residual add (optional) + optional convpass-up add + LayerNorm
// -> fp32 xout (optional) + bf16 hout
// ---------------------------------------------------------------------------
__global__ __launch_bounds__(256) void k_addln(
    const float* __restrict__ x, const float* __restrict__ pos,
    const float* __restrict__ g, const float* __restrict__ be,
    float* __restrict__ xout, bf16_t* __restrict__ hout,
    const float* __restrict__ cpv, const float* __restrict__ uwp,
    const float* __restrict__ ubp)
{
    int row = blockIdx.x, tid = threadIdx.x;
    size_t base = (size_t)row * kC;
    __shared__ float s8[8];
    if (cpv) {
        if (tid < 8) s8[tid] = cpv[(size_t)row * 8 + tid];
        __syncthreads();
    }
    float v0 = x[base + tid], v1 = x[base + tid + 256];
    if (pos) { v0 += pos[base + tid]; v1 += pos[base + tid + 256]; }
    if (cpv) {
        float u0 = ubp[tid], u1 = ubp[tid + 256];
        #pragma unroll
        for (int a = 0; a < 8; a++) {
            u0 += s8[a] * uwp[a * kC + tid];
            u1 += s8[a] * uwp[a * kC + tid + 256];
        }
        v0 += u0; v1 += u1;
    }
    if (xout) { xout[base + tid] = v0; xout[base + tid + 256] = v1; }
    float s = v0 + v1, q = v0 * v0 + v1 * v1;
    #pragma unroll
    for (int o = 32; o > 0; o >>= 1) {
        s += __shfl_down(s, o);
        q += __shfl_down(q, o);
    }
    __shared__ float ss[4], sq[4], mrs[2];
    int wv = tid >> 6, ln = tid & 63;
    if (!ln) { ss[wv] = s; sq[wv] = q; }
    __syncthreads();
    if (!tid) {
        float ts = ss[0] + ss[1] + ss[2] + ss[3];
        float tq = sq[0] + sq[1] + sq[2] + sq[3];
        float m = ts * (1.f / kC);
        float var = tq * (1.f / kC) - m * m;
        mrs[0] = m; mrs[1] = rsqrtf(var + kEPS);
    }
    __syncthreads();
    float m = mrs[0], r = mrs[1];
    hout[base + tid]       = (bf16_t)((v0 - m) * r * g[tid] + be[tid]);
    hout[base + tid + 256] = (bf16_t)((v1 - m) * r * g[tid + 256] + be[tid + 256]);
}

// ---------------------------------------------------------------------------
// all 4 weight transposes (fp32 [K][N] -> bf16 [N][K]) in one dispatch
// ---------------------------------------------------------------------------
__global__ __launch_bounds__(256) void k_transpose_all(
    const float* __restrict__ qkvw, const float* __restrict__ projw,
    const float* __restrict__ fw1,  const float* __restrict__ fw2,
    bf16_t* __restrict__ qkvT, bf16_t* __restrict__ projT,
    bf16_t* __restrict__ fw1T, bf16_t* __restrict__ fw2T)
{
    int id = blockIdx.x;
    const float* w; bf16_t* wt; int K, N, bx, by;
    if (id < 768)       { w = qkvw; wt = qkvT; K = 512;  N = 1536; bx = id % 48;  by = id / 48; }
    else if (id < 1024) { id -= 768;  w = projw; wt = projT; K = 512;  N = 512;  bx = id % 16;  by = id / 16; }
    else if (id < 3072) { id -= 1024; w = fw1;   wt = fw1T;  K = 512;  N = 4096; bx = id % 128; by = id / 128; }
    else                { id -= 3072; w = fw2;   wt = fw2T;  K = 4096; N = 512;  bx = id % 16;  by = id / 16; }
    __shared__ float t[32][33];
    int n0 = bx * 32, k0 = by * 32;
    int tx = threadIdx.x & 31, ty = threadIdx.x >> 5;   // 32 x 8
    #pragma unroll
    for (int j = 0; j < 32; j += 8)
        t[ty + j][tx] = w[(size_t)(k0 + ty + j) * N + n0 + tx];
    __syncthreads();
    #pragma unroll
    for (int j = 0; j < 32; j += 8)
        wt[(size_t)(n0 + ty + j) * K + k0 + tx] = (bf16_t)t[tx][ty + j];
}

// ---------------------------------------------------------------------------
// bf16 MFMA GEMM: C = [res +] act(A[M,K] @ Bt[N,K]^T [+ bias])
// 128x128 tile, BK=64 (two BK=32 tile-pairs per barrier), 256 thr = 4 waves.
// OMODE: 0 = fp32 out, 1 = bf16 out, 2 = bf16 scatter to qkv blocked layout.
// ldA/ldB: row strides of A and Bt (for K-chunked weights).
// ---------------------------------------------------------------------------
template <int ACT, bool HASB, bool HASR, int OMODE>
__global__ __launch_bounds__(256) void k_gemm(
    const bf16_t* __restrict__ A, const bf16_t* __restrict__ Bt,
    const float* __restrict__ bias, const float* __restrict__ res,
    void* __restrict__ outv, int M, int K, int ldA, int ldB, int Nc)
{
    __shared__ bf16_t As[2][128 * 32];
    __shared__ bf16_t Bs[2][128 * 32];
    int tid = threadIdx.x;
    int col0 = blockIdx.x * 128, row0 = blockIdx.y * 128;
    int w = tid >> 6, l = tid & 63;
    int rw0 = (w & 1) * 64, cw0 = (w >> 1) * 64;
    int lr = tid >> 2, lc = (tid & 3) * 8;

    f32x4 acc[4][4];
    #pragma unroll
    for (int i = 0; i < 4; i++)
        #pragma unroll
        for (int j = 0; j < 4; j++)
            acc[i][j] = (f32x4){0.f, 0.f, 0.f, 0.f};

    const bf16_t* Ag  = A  + (size_t)(row0 + lr) * ldA + lc;
    const bf16_t* Ag2 = A  + (size_t)(row0 + 64 + lr) * ldA + lc;
    const bf16_t* Bg  = Bt + (size_t)(col0 + lr) * ldB + lc;
    const bf16_t* Bg2 = Bt + (size_t)(col0 + 64 + lr) * ldB + lc;

    int am = rw0 + (l & 15);
    int bn = cw0 + (l & 15);
    int kq = (l >> 4) * 8;

    for (int k0 = 0; k0 < K; k0 += 64) {
        gld_lds16(Ag + k0, &As[0][tid * 8]);
        gld_lds16(Ag2 + k0, &As[0][2048 + tid * 8]);
        gld_lds16(Bg + k0, &Bs[0][tid * 8]);
        gld_lds16(Bg2 + k0, &Bs[0][2048 + tid * 8]);
        gld_lds16(Ag + k0 + 32, &As[1][tid * 8]);
        gld_lds16(Ag2 + k0 + 32, &As[1][2048 + tid * 8]);
        gld_lds16(Bg + k0 + 32, &Bs[1][tid * 8]);
        gld_lds16(Bg2 + k0 + 32, &Bs[1][2048 + tid * 8]);
        __syncthreads();
        #pragma unroll
        for (int ks = 0; ks < 2; ks++) {
            bf16x8 af[4], bfr[4];
            #pragma unroll
            for (int mt = 0; mt < 4; mt++)
                af[mt] = *(const bf16x8*)&As[ks][(am + mt * 16) * 32 + kq];
            #pragma unroll
            for (int nt = 0; nt < 4; nt++)
                bfr[nt] = *(const bf16x8*)&Bs[ks][(bn + nt * 16) * 32 + kq];
            #pragma unroll
            for (int mt = 0; mt < 4; mt++)
                #pragma unroll
                for (int nt = 0; nt < 4; nt++)
                    acc[mt][nt] = __builtin_amdgcn_mfma_f32_16x16x32_bf16(
                        af[mt], bfr[nt], acc[mt][nt], 0, 0, 0);
        }
        __syncthreads();
    }

    #pragma unroll
    for (int mt = 0; mt < 4; mt++) {
        int rowb = row0 + rw0 + mt * 16 + (l >> 4) * 4;
        #pragma unroll
        for (int nt = 0; nt < 4; nt++) {
            int col = col0 + cw0 + nt * 16 + (l & 15);
            float bv = HASB ? bias[col] : 0.f;
            #pragma unroll
            for (int p = 0; p < 4; p++) {
                float v = acc[mt][nt][p] + bv;
                if (ACT == 1) v = qgelu_f(v);
                if (ACT == 2) v = gelu_f(v);
                int r = rowb + p;
                if (OMODE == 0) {
                    if (HASR) v += res[(size_t)r * Nc + col];
                    ((float*)outv)[(size_t)r * Nc + col] = v;
                } else if (OMODE == 1) {
                    ((bf16_t*)outv)[(size_t)r * Nc + col] = (bf16_t)v;
                } else {
                    int bb = r >> 9, n = r & 511;
                    int which = col >> 9, hd = (col >> 6) & 7, d = col & 63;
                    ((bf16_t*)outv)[(((size_t)(bb * 8 + hd) * 3 + which) << 15)
                                    + n * 64 + d] = (bf16_t)v;
                }
            }
        }
    }
}

// ---------------------------------------------------------------------------
// MFMA flash attention. qkvb layout: [(b*8+h)*3 + {q,k,v}][n][64] bf16.
// ---------------------------------------------------------------------------
__global__ __launch_bounds__(256) void k_attn(
    const bf16_t* __restrict__ qkvb, bf16_t* __restrict__ obuf)
{
    __shared__ bf16_t Ks[64 * 72];
    __shared__ bf16_t Vt[64 * 72];
    __shared__ bf16_t Ps[4][32 * 72];
    int bid = blockIdx.x;
    int qb = bid & 3, h = (bid >> 2) & 7, b = bid >> 5;
    int t = threadIdx.x, w = t >> 6, l = t & 63;
    const bf16_t* qp = qkvb + (((size_t)(b * 8 + h) * 3) << 15);
    const bf16_t* kp = qp + (1 << 15);
    const bf16_t* vp = qp + (2 << 15);
    int q0 = qb * 128 + w * 32;
    int l15 = l & 15, lq = (l >> 4) * 8;

    bf16x8 aq[2][2];
    #pragma unroll
    for (int mt = 0; mt < 2; mt++)
        #pragma unroll
        for (int kh = 0; kh < 2; kh++)
            aq[mt][kh] = *(const bf16x8*)(qp + (size_t)(q0 + mt * 16 + l15) * 64
                                          + kh * 32 + lq);

    f32x4 o[2][4];
    float m_run[2][4], l_run[2][4];
    #pragma unroll
    for (int mt = 0; mt < 2; mt++) {
        #pragma unroll
        for (int dt = 0; dt < 4; dt++) o[mt][dt] = (f32x4){0.f, 0.f, 0.f, 0.f};
        #pragma unroll
        for (int p = 0; p < 4; p++) { m_run[mt][p] = -1e30f; l_run[mt][p] = 0.f; }
    }

    int sr = t >> 2, scc = (t & 3) * 16;
    for (int kt = 0; kt < 8; kt++) {
        if (kt) __syncthreads();
        {
            const bf16_t* ks = kp + (size_t)(kt * 64 + sr) * 64 + scc;
            *(uint4*)&Ks[sr * 72 + scc]     = *(const uint4*)ks;
            *(uint4*)&Ks[sr * 72 + scc + 8] = *(const uint4*)(ks + 8);
            const bf16_t* vs = vp + (size_t)(kt * 64 + sr) * 64 + scc;
            bf16x8 v0 = *(const bf16x8*)vs;
            bf16x8 v1 = *(const bf16x8*)(vs + 8);
            #pragma unroll
            for (int e = 0; e < 8; e++) {
                Vt[(scc + e) * 72 + sr]     = v0[e];
                Vt[(scc + 8 + e) * 72 + sr] = v1[e];
            }
        }
        __syncthreads();
        #pragma unroll
        for (int mt = 0; mt < 2; mt++) {
            f32x4 sc[4];
            #pragma unroll
            for (int nt = 0; nt < 4; nt++) sc[nt] = (f32x4){0.f, 0.f, 0.f, 0.f};
            #pragma unroll
            for (int nt = 0; nt < 4; nt++)
                #pragma unroll
                for (int kh = 0; kh < 2; kh++) {
                    bf16x8 bk = *(const bf16x8*)&Ks[(nt * 16 + l15) * 72
                                                    + kh * 32 + lq];
                    sc[nt] = __builtin_amdgcn_mfma_f32_16x16x32_bf16(
                        aq[mt][kh], bk, sc[nt], 0, 0, 0);
                }
            #pragma unroll
            for (int nt = 0; nt < 4; nt++)
                #pragma unroll
                for (int p = 0; p < 4; p++) sc[nt][p] *= kSCALE;

            float mx[4], alpha[4], rs[4];
            #pragma unroll
            for (int p = 0; p < 4; p++) {
                float m4 = fmaxf(fmaxf(sc[0][p], sc[1][p]),
                                 fmaxf(sc[2][p], sc[3][p]));
                #pragma unroll
                for (int off = 1; off < 16; off <<= 1)
                    m4 = fmaxf(m4, __shfl_xor(m4, off));
                float mn = fmaxf(m_run[mt][p], m4);
                alpha[p] = __expf(m_run[mt][p] - mn);
                m_run[mt][p] = mn;
                mx[p] = mn;
                rs[p] = 0.f;
            }
            int prow = mt * 16 + (l >> 4) * 4;
            #pragma unroll
            for (int nt = 0; nt < 4; nt++)
                #pragma unroll
                for (int p = 0; p < 4; p++) {
                    float pv = __expf(sc[nt][p] - mx[p]);
                    rs[p] += pv;
                    Ps[w][(prow + p) * 72 + nt * 16 + l15] = (bf16_t)pv;
                }
            #pragma unroll
            for (int p = 0; p < 4; p++) {
                float r = rs[p];
                #pragma unroll
                for (int off = 1; off < 16; off <<= 1)
                    r += __shfl_xor(r, off);
                l_run[mt][p] = l_run[mt][p] * alpha[p] + r;
                #pragma unroll
                for (int dt = 0; dt < 4; dt++) o[mt][dt][p] *= alpha[p];
            }
            bf16x8 ap[2];
            #pragma unroll
            for (int kh = 0; kh < 2; kh++)
                ap[kh] = *(const bf16x8*)&Ps[w][(mt * 16 + l15) * 72
                                                + kh * 32 + lq];
            #pragma unroll
            for (int dt = 0; dt < 4; dt++)
                #pragma unroll
                for (int kh = 0; kh < 2; kh++) {
                    bf16x8 bv = *(const bf16x8*)&Vt[(dt * 16 + l15) * 72
                                                    + kh * 32 + lq];
                    o[mt][dt] = __builtin_amdgcn_mfma_f32_16x16x32_bf16(
                        ap[kh], bv, o[mt][dt], 0, 0, 0);
                }
        }
    }
    #pragma unroll
    for (int mt = 0; mt < 2; mt++)
        #pragma unroll
        for (int dt = 0; dt < 4; dt++)
            #pragma unroll
            for (int p = 0; p < 4; p++) {
                int q = q0 + mt * 16 + (l >> 4) * 4 + p;
                int col = h * 64 + dt * 16 + l15;
                float v = o[mt][dt][p] / l_run[mt][p];
                obuf[((size_t)b * 512 + q) * 512 + col] = (bf16_t)v;
            }
}

// ---------------------------------------------------------------------------
// Convpass down (bf16 h): cpa[row][a] = qgelu(h[row,:] @ dw[:,a] + db[a])
// ---------------------------------------------------------------------------
__global__ __launch_bounds__(256) void k_down(
    const bf16_t* __restrict__ h, const float* __restrict__ dw,
    const float* __restrict__ db, float* __restrict__ outp)
{
    __shared__ float sdw[kC * kAD];
    int t = threadIdx.x;
    for (int i = t; i < kC * kAD; i += 256) sdw[i] = dw[i];
    __syncthreads();
    int gt = blockIdx.x * 256 + t;
    int row = gt >> 3, a = gt & 7;
    const bf16x8* hr = (const bf16x8*)(h + (size_t)row * kC);
    float acc = 0.f;
    for (int k8 = 0; k8 < kC / 8; k8++) {
        bf16x8 hv = hr[k8];
        #pragma unroll
        for (int e = 0; e < 8; e++)
            acc += (float)hv[e] * sdw[(k8 * 8 + e) * kAD + a];
    }
    outp[gt] = qgelu_f(acc + db[a]);
}

// ---------------------------------------------------------------------------
// 3x3x3 SAME conv over 8x8x8, 8->8 ch, + bias, qgelu
// ---------------------------------------------------------------------------
__global__ __launch_bounds__(512) void k_conv(
    const float* __restrict__ inp, const float* __restrict__ cw,
    const float* __restrict__ cb, float* __restrict__ outp)
{
    __shared__ float si[512 * 9];
    __shared__ float sw[8 * 8 * 27];
    int b = blockIdx.x, t = threadIdx.x;
    for (int i = t; i < 512 * 8; i += 512) {
        int n = i >> 3, a = i & 7;
        si[n * 9 + a] = inp[(size_t)b * 4096 + i];
    }
    for (int i = t; i < 1728; i += 512) sw[i] = cw[i];
    __syncthreads();
    int z = t >> 6, y = (t >> 3) & 7, xx = t & 7;
    float acc[8];
    #pragma unroll
    for (int ao = 0; ao < 8; ao++) acc[ao] = cb[ao];
    for (int dz = -1; dz <= 1; dz++) {
        int zz = z + dz; if ((unsigned)zz > 7u) continue;
        for (int dy = -1; dy <= 1; dy++) {
            int yy = y + dy; if ((unsigned)yy > 7u) continue;
            for (int dx = -1; dx <= 1; dx++) {
                int xn = xx + dx; if ((unsigned)xn > 7u) continue;
                int nn = zz * 64 + yy * 8 + xn;
                int wo = ((dz + 1) * 3 + (dy + 1)) * 3 + (dx + 1);
                #pragma unroll
                for (int ai = 0; ai < 8; ai++) {
                    float iv = si[nn * 9 + ai];
                    #pragma unroll
                    for (int ao = 0; ao < 8; ao++)
                        acc[ao] += iv * sw[(ao * 8 + ai) * 27 + wo];
                }
            }
        }
    }
    #pragma unroll
    for (int ao = 0; ao < 8; ao++)
        outp[(size_t)b * 4096 + t * 8 + ao] = qgelu_f(acc[ao]);
}

// ---------------------------------------------------------------------------
// Convpass up: xbuf[row][c] += pa[row,:] @ uw[:,c] + ub[c]
// ---------------------------------------------------------------------------
__global__ __launch_bounds__(256) void k_up(
    const float* __restrict__ pa, const float* __restrict__ uw,
    const float* __restrict__ ub, float* __restrict__ xbuf)
{
    __shared__ float s[8];
    int row = blockIdx.x, t = threadIdx.x;
    if (t < 8) s[t] = pa[(size_t)row * kAD + t];
    __syncthreads();
    #pragma unroll
    for (int rep = 0; rep < 2; rep++) {
        int c = t + rep * 256;
        float acc = ub[c];
        #pragma unroll
        for (int a = 0; a < 8; a++) acc += s[a] * uw[a * kC + c];
        xbuf[(size_t)row * kC + c] += acc;
    }
}

// ---------------------------------------------------------------------------
extern "C" void kernel_launch(void* const* d_in, const int* in_sizes, int n_in,
                              void* d_out, int out_size, void* d_ws, size_t ws_size,
                              hipStream_t stream)
{
    const float* x     = (const float*)d_in[0];
    const float* pos   = (const float*)d_in[1];
    const float* ln1g  = (const float*)d_in[2];
    const float* ln1b  = (const float*)d_in[3];
    const float* qkvw  = (const float*)d_in[4];
    const float* projw = (const float*)d_in[5];
    const float* projb = (const float*)d_in[6];
    const float* dw1   = (const float*)d_in[7];
    const float* db1   = (const float*)d_in[8];
    const float* cw1   = (const float*)d_in[9];
    const float* cb1   = (const float*)d_in[10];
    const float* uw1   = (const float*)d_in[11];
    const float* ub1   = (const float*)d_in[12];
    const float* ln2g  = (const float*)d_in[13];
    const float* ln2b  = (const float*)d_in[14];
    const float* fw1   = (const float*)d_in[15];
    const float* fb1   = (const float*)d_in[16];
    const float* fw2   = (const float*)d_in[17];
    const float* fb2   = (const float*)d_in[18];
    const float* dw2   = (const float*)d_in[19];
    const float* db2   = (const float*)d_in[20];
    const float* cw2   = (const float*)d_in[21];
    const float* cb2   = (const float*)d_in[22];
    const float* uw2   = (const float*)d_in[23];
    const float* ub2   = (const float*)d_in[24];
    float* out = (float*)d_out;

    char* wsb = (char*)d_ws;
    float*  xbuf = (float*)wsb;
    bf16_t* hb   = (bf16_t*)(wsb + 33554432);
    bf16_t* obuf = (bf16_t*)(wsb + 50331648);
    bf16_t* qkvb = (bf16_t*)(wsb + 67108864);
    bf16_t* midb = (bf16_t*)(wsb + 50331648);   // stage-3 alias: [16384][2048]
    bf16_t* qkvT = (bf16_t*)(wsb + 117440512);  // [1536][512]
    bf16_t* projT= (bf16_t*)(wsb + 119013376);  // [512][512]
    bf16_t* fw1T = (bf16_t*)(wsb + 119537664);  // [4096][512]
    bf16_t* fw2T = (bf16_t*)(wsb + 123731968);  // [512][4096]
    float*  cpa  = (float*)(wsb + 127926272);
    float*  cpb  = (float*)(wsb + 128450560);

    // all weight transposes (fp32 -> bf16 B^T form), one dispatch
    k_transpose_all<<<5120, 256, 0, stream>>>(
        qkvw, projw, fw1, fw2, qkvT, projT, fw1T, fw2T);

    // stage 1: xbuf = x + pos; hb = LN1(xbuf)
    k_addln<<<kBN, 256, 0, stream>>>(x, pos, ln1g, ln1b, xbuf, hb,
                                     nullptr, nullptr, nullptr);

    // QKV -> blocked bf16 layout, flash attention, proj (+bias +residual)
    k_gemm<0, false, false, 2><<<dim3(12, 128), 256, 0, stream>>>(
        hb, qkvT, nullptr, nullptr, qkvb, kBN, 512, 512, 512, 1536);
    k_attn<<<kB * kH * 4, 256, 0, stream>>>(qkvb, obuf);
    k_gemm<0, true, true, 0><<<dim3(4, 128), 256, 0, stream>>>(
        obuf, projT, projb, xbuf, xbuf, kBN, 512, 512, 512, 512);

    // convpass 1 (on hb): down + conv; up is folded into the next addln
    k_down<<<kBN * kAD / 256, 256, 0, stream>>>(hb, dw1, db1, cpa);
    k_conv<<<kB, 512, 0, stream>>>(cpa, cw1, cb1, cpb);

    // stage 2: xbuf += cp1_up(cpb); hb = LN2(xbuf)
    k_addln<<<kBN, 256, 0, stream>>>(xbuf, nullptr, ln2g, ln2b, xbuf, hb,
                                     cpb, uw1, ub1);

    // convpass 2, accumulate into xbuf
    k_down<<<kBN * kAD / 256, 256, 0, stream>>>(hb, dw2, db2, cpa);
    k_conv<<<kB, 512, 0, stream>>>(cpa, cw2, cb2, cpb);
    k_up<<<kBN, 256, 0, stream>>>(cpb, uw2, ub2, xbuf);

    // FFN, K-chunked (2 x 2048 mid cols), full M=16384 per dispatch.
    k_gemm<2, true, false, 1><<<dim3(16, 128), 256, 0, stream>>>(
        hb, fw1T, fb1, nullptr, midb, kBN, 512, 512, 512, 2048);
    k_gemm<0, false, true, 0><<<dim3(4, 128), 256, 0, stream>>>(
        midb, fw2T, nullptr, xbuf, xbuf, kBN, 2048, 2048, 4096, 512);
    k_gemm<2, true, false, 1><<<dim3(16, 128), 256, 0, stream>>>(
        hb, fw1T + (size_t)2048 * 512, fb1 + 2048, nullptr, midb,
        kBN, 512, 512, 512, 2048);
    k_gemm<0, true, true, 0><<<dim3(4, 128), 256, 0, stream>>>(
        midb, fw2T + 2048, fb2, xbuf, out, kBN, 2048, 2048, 4096, 512);
}

// Round 6
// 635.677 us; speedup vs baseline: 7.4006x; 1.0528x over previous
//
#include <hip/hip_runtime.h>
#include <math.h>

typedef __bf16 bf16_t;
typedef __bf16 bf16x8 __attribute__((ext_vector_type(8)));
typedef float f32x4 __attribute__((ext_vector_type(4)));

constexpr int kB   = 32;
constexpr int kN   = 512;
constexpr int kC   = 512;
constexpr int kH   = 8;
constexpr int kAD  = 8;
constexpr int kMLP = 4096;
constexpr int kBN  = kB * kN;          // 16384 rows
constexpr float kEPS   = 1e-5f;
constexpr float kSCALE = 0.125f;       // DH^-0.5

__device__ __forceinline__ float qgelu_f(float x) {
    return x / (1.f + __expf(-1.702f * x));
}
// tanh-approx gelu: max |err| vs exact erf-gelu ~3e-4, well under threshold.
__device__ __forceinline__ float gelu_f(float x) {
    float u = 1.5957691216f * x * (1.f + 0.044715f * x * x);
    float e = __expf(u);
    float th = 1.f - 2.f / (e + 1.f);
    return 0.5f * x * (1.f + th);
}

// async global->LDS, 16 bytes per lane. LDS dest must be uniform-base+lane*16.
__device__ __forceinline__ void gld_lds16(const void* g, void* l) {
    typedef const __attribute__((address_space(1))) unsigned int* gp_t;
    typedef __attribute__((address_space(3))) unsigned int* lp_t;
    __builtin_amdgcn_global_load_lds((gp_t)(unsigned long long)g,
                                     (lp_t)(unsigned)(unsigned long long)l,
                                     16, 0, 0);
}

// ---------------------------------------------------------------------------
// residual add (optional) + optional convpass-up add + LayerNorm
// -> fp32 xout (optional) + bf16 hout
// ---------------------------------------------------------------------------
__global__ __launch_bounds__(256) void k_addln(
    const float* __restrict__ x, const float* __restrict__ pos,
    const float* __restrict__ g, const float* __restrict__ be,
    float* __restrict__ xout, bf16_t* __restrict__ hout,
    const float* __restrict__ cpv, const float* __restrict__ uwp,
    const float* __restrict__ ubp)
{
    int row = blockIdx.x, tid = threadIdx.x;
    size_t base = (size_t)row * kC;
    __shared__ float s8[8];
    if (cpv) {
        if (tid < 8) s8[tid] = cpv[(size_t)row * 8 + tid];
        __syncthreads();
    }
    float v0 = x[base + tid], v1 = x[base + tid + 256];
    if (pos) { v0 += pos[base + tid]; v1 += pos[base + tid + 256]; }
    if (cpv) {
        float u0 = ubp[tid], u1 = ubp[tid + 256];
        #pragma unroll
        for (int a = 0; a < 8; a++) {
            u0 += s8[a] * uwp[a * kC + tid];
            u1 += s8[a] * uwp[a * kC + tid + 256];
        }
        v0 += u0; v1 += u1;
    }
    if (xout) { xout[base + tid] = v0; xout[base + tid + 256] = v1; }
    float s = v0 + v1, q = v0 * v0 + v1 * v1;
    #pragma unroll
    for (int o = 32; o > 0; o >>= 1) {
        s += __shfl_down(s, o);
        q += __shfl_down(q, o);
    }
    __shared__ float ss[4], sq[4], mrs[2];
    int wv = tid >> 6, ln = tid & 63;
    if (!ln) { ss[wv] = s; sq[wv] = q; }
    __syncthreads();
    if (!tid) {
        float ts = ss[0] + ss[1] + ss[2] + ss[3];
        float tq = sq[0] + sq[1] + sq[2] + sq[3];
        float m = ts * (1.f / kC);
        float var = tq * (1.f / kC) - m * m;
        mrs[0] = m; mrs[1] = rsqrtf(var + kEPS);
    }
    __syncthreads();
    float m = mrs[0], r = mrs[1];
    hout[base + tid]       = (bf16_t)((v0 - m) * r * g[tid] + be[tid]);
    hout[base + tid + 256] = (bf16_t)((v1 - m) * r * g[tid + 256] + be[tid + 256]);
}

// ---------------------------------------------------------------------------
// all 4 weight transposes (fp32 [K][N] -> bf16 [N][K]) in one dispatch
// ---------------------------------------------------------------------------
__global__ __launch_bounds__(256) void k_transpose_all(
    const float* __restrict__ qkvw, const float* __restrict__ projw,
    const float* __restrict__ fw1,  const float* __restrict__ fw2,
    bf16_t* __restrict__ qkvT, bf16_t* __restrict__ projT,
    bf16_t* __restrict__ fw1T, bf16_t* __restrict__ fw2T)
{
    int id = blockIdx.x;
    const float* w; bf16_t* wt; int K, N, bx, by;
    if (id < 768)       { w = qkvw; wt = qkvT; K = 512;  N = 1536; bx = id % 48;  by = id / 48; }
    else if (id < 1024) { id -= 768;  w = projw; wt = projT; K = 512;  N = 512;  bx = id % 16;  by = id / 16; }
    else if (id < 3072) { id -= 1024; w = fw1;   wt = fw1T;  K = 512;  N = 4096; bx = id % 128; by = id / 128; }
    else                { id -= 3072; w = fw2;   wt = fw2T;  K = 4096; N = 512;  bx = id % 16;  by = id / 16; }
    __shared__ float t[32][33];
    int n0 = bx * 32, k0 = by * 32;
    int tx = threadIdx.x & 31, ty = threadIdx.x >> 5;   // 32 x 8
    #pragma unroll
    for (int j = 0; j < 32; j += 8)
        t[ty + j][tx] = w[(size_t)(k0 + ty + j) * N + n0 + tx];
    __syncthreads();
    #pragma unroll
    for (int j = 0; j < 32; j += 8)
        wt[(size_t)(n0 + ty + j) * K + k0 + tx] = (bf16_t)t[tx][ty + j];
}

// ---------------------------------------------------------------------------
// bf16 MFMA GEMM: C = [res +] act(A[M,K] @ Bt[N,K]^T [+ bias])
// 128x128 tile, BK=64, 256 thr = 4 waves. Compile-time K/LDA/LDB/NC.
// LDS k-chunk XOR swizzle: physical chunk = logical ^ ((row>>1)&3), applied
// on the global-source side of global_load_lds; fragment reads XOR back.
// -> fragment ds_read_b128 conflicts drop from 8-way to 2-way (free).
// OMODE: 0 = fp32 out, 1 = bf16 out, 2 = bf16 scatter to qkv blocked layout.
// ---------------------------------------------------------------------------
template <int ACT, bool HASB, bool HASR, int OMODE, int K, int LDA, int LDB, int NC>
__global__ __launch_bounds__(256) void k_gemm(
    const bf16_t* __restrict__ A, const bf16_t* __restrict__ Bt,
    const float* __restrict__ bias, const float* __restrict__ res,
    void* __restrict__ outv)
{
    __shared__ bf16_t As[2][128 * 32];
    __shared__ bf16_t Bs[2][128 * 32];
    int tid = threadIdx.x;
    int col0 = blockIdx.x * 128, row0 = blockIdx.y * 128;
    int w = tid >> 6, l = tid & 63;
    int rw0 = (w & 1) * 64, cw0 = (w >> 1) * 64;
    int lr = tid >> 2;
    // swizzled k-chunk for staging: slot (tid&3) holds logical chunk
    // (tid&3) ^ swz(row), swz(row) = (row>>1)&3 = (tid>>3)&3
    int lc = (((tid & 3) ^ ((tid >> 3) & 3)) * 8);

    f32x4 acc[4][4];
    #pragma unroll
    for (int i = 0; i < 4; i++)
        #pragma unroll
        for (int j = 0; j < 4; j++)
            acc[i][j] = (f32x4){0.f, 0.f, 0.f, 0.f};

    const bf16_t* Ag  = A  + (size_t)(row0 + lr) * LDA + lc;
    const bf16_t* Ag2 = A  + (size_t)(row0 + 64 + lr) * LDA + lc;
    const bf16_t* Bg  = Bt + (size_t)(col0 + lr) * LDB + lc;
    const bf16_t* Bg2 = Bt + (size_t)(col0 + 64 + lr) * LDB + lc;

    int am = rw0 + (l & 15);
    int bn = cw0 + (l & 15);
    int kq = (l >> 4) * 8;
    int kqA = kq ^ (((am >> 1) & 3) << 3);   // un-swizzle on read
    int kqB = kq ^ (((bn >> 1) & 3) << 3);

    for (int k0 = 0; k0 < K; k0 += 64) {
        gld_lds16(Ag + k0, &As[0][tid * 8]);
        gld_lds16(Ag2 + k0, &As[0][2048 + tid * 8]);
        gld_lds16(Bg + k0, &Bs[0][tid * 8]);
        gld_lds16(Bg2 + k0, &Bs[0][2048 + tid * 8]);
        gld_lds16(Ag + k0 + 32, &As[1][tid * 8]);
        gld_lds16(Ag2 + k0 + 32, &As[1][2048 + tid * 8]);
        gld_lds16(Bg + k0 + 32, &Bs[1][tid * 8]);
        gld_lds16(Bg2 + k0 + 32, &Bs[1][2048 + tid * 8]);
        __syncthreads();
        #pragma unroll
        for (int ks = 0; ks < 2; ks++) {
            bf16x8 af[4], bfr[4];
            #pragma unroll
            for (int mt = 0; mt < 4; mt++)
                af[mt] = *(const bf16x8*)&As[ks][(am + mt * 16) * 32 + kqA];
            #pragma unroll
            for (int nt = 0; nt < 4; nt++)
                bfr[nt] = *(const bf16x8*)&Bs[ks][(bn + nt * 16) * 32 + kqB];
            #pragma unroll
            for (int mt = 0; mt < 4; mt++)
                #pragma unroll
                for (int nt = 0; nt < 4; nt++)
                    acc[mt][nt] = __builtin_amdgcn_mfma_f32_16x16x32_bf16(
                        af[mt], bfr[nt], acc[mt][nt], 0, 0, 0);
        }
        __syncthreads();
    }

    #pragma unroll
    for (int mt = 0; mt < 4; mt++) {
        int rowb = row0 + rw0 + mt * 16 + (l >> 4) * 4;
        #pragma unroll
        for (int nt = 0; nt < 4; nt++) {
            int col = col0 + cw0 + nt * 16 + (l & 15);
            float bv = HASB ? bias[col] : 0.f;
            #pragma unroll
            for (int p = 0; p < 4; p++) {
                float v = acc[mt][nt][p] + bv;
                if (ACT == 1) v = qgelu_f(v);
                if (ACT == 2) v = gelu_f(v);
                int r = rowb + p;
                if (OMODE == 0) {
                    if (HASR) v += res[(size_t)r * NC + col];
                    ((float*)outv)[(size_t)r * NC + col] = v;
                } else if (OMODE == 1) {
                    ((bf16_t*)outv)[(size_t)r * NC + col] = (bf16_t)v;
                } else {
                    int bb = r >> 9, n = r & 511;
                    int which = col >> 9, hd = (col >> 6) & 7, d = col & 63;
                    ((bf16_t*)outv)[(((size_t)(bb * 8 + hd) * 3 + which) << 15)
                                    + n * 64 + d] = (bf16_t)v;
                }
            }
        }
    }
}

// ---------------------------------------------------------------------------
// MFMA flash attention. qkvb layout: [(b*8+h)*3 + {q,k,v}][n][64] bf16.
// ---------------------------------------------------------------------------
__global__ __launch_bounds__(256) void k_attn(
    const bf16_t* __restrict__ qkvb, bf16_t* __restrict__ obuf)
{
    __shared__ bf16_t Ks[64 * 72];
    __shared__ bf16_t Vt[64 * 72];
    __shared__ bf16_t Ps[4][32 * 72];
    int bid = blockIdx.x;
    int qb = bid & 3, h = (bid >> 2) & 7, b = bid >> 5;
    int t = threadIdx.x, w = t >> 6, l = t & 63;
    const bf16_t* qp = qkvb + (((size_t)(b * 8 + h) * 3) << 15);
    const bf16_t* kp = qp + (1 << 15);
    const bf16_t* vp = qp + (2 << 15);
    int q0 = qb * 128 + w * 32;
    int l15 = l & 15, lq = (l >> 4) * 8;

    bf16x8 aq[2][2];
    #pragma unroll
    for (int mt = 0; mt < 2; mt++)
        #pragma unroll
        for (int kh = 0; kh < 2; kh++)
            aq[mt][kh] = *(const bf16x8*)(qp + (size_t)(q0 + mt * 16 + l15) * 64
                                          + kh * 32 + lq);

    f32x4 o[2][4];
    float m_run[2][4], l_run[2][4];
    #pragma unroll
    for (int mt = 0; mt < 2; mt++) {
        #pragma unroll
        for (int dt = 0; dt < 4; dt++) o[mt][dt] = (f32x4){0.f, 0.f, 0.f, 0.f};
        #pragma unroll
        for (int p = 0; p < 4; p++) { m_run[mt][p] = -1e30f; l_run[mt][p] = 0.f; }
    }

    int sr = t >> 2, scc = (t & 3) * 16;
    for (int kt = 0; kt < 8; kt++) {
        if (kt) __syncthreads();
        {
            const bf16_t* ks = kp + (size_t)(kt * 64 + sr) * 64 + scc;
            *(uint4*)&Ks[sr * 72 + scc]     = *(const uint4*)ks;
            *(uint4*)&Ks[sr * 72 + scc + 8] = *(const uint4*)(ks + 8);
            const bf16_t* vs = vp + (size_t)(kt * 64 + sr) * 64 + scc;
            bf16x8 v0 = *(const bf16x8*)vs;
            bf16x8 v1 = *(const bf16x8*)(vs + 8);
            #pragma unroll
            for (int e = 0; e < 8; e++) {
                Vt[(scc + e) * 72 + sr]     = v0[e];
                Vt[(scc + 8 + e) * 72 + sr] = v1[e];
            }
        }
        __syncthreads();
        #pragma unroll
        for (int mt = 0; mt < 2; mt++) {
            f32x4 sc[4];
            #pragma unroll
            for (int nt = 0; nt < 4; nt++) sc[nt] = (f32x4){0.f, 0.f, 0.f, 0.f};
            #pragma unroll
            for (int nt = 0; nt < 4; nt++)
                #pragma unroll
                for (int kh = 0; kh < 2; kh++) {
                    bf16x8 bk = *(const bf16x8*)&Ks[(nt * 16 + l15) * 72
                                                    + kh * 32 + lq];
                    sc[nt] = __builtin_amdgcn_mfma_f32_16x16x32_bf16(
                        aq[mt][kh], bk, sc[nt], 0, 0, 0);
                }
            #pragma unroll
            for (int nt = 0; nt < 4; nt++)
                #pragma unroll
                for (int p = 0; p < 4; p++) sc[nt][p] *= kSCALE;

            float mx[4], alpha[4], rs[4];
            #pragma unroll
            for (int p = 0; p < 4; p++) {
                float m4 = fmaxf(fmaxf(sc[0][p], sc[1][p]),
                                 fmaxf(sc[2][p], sc[3][p]));
                #pragma unroll
                for (int off = 1; off < 16; off <<= 1)
                    m4 = fmaxf(m4, __shfl_xor(m4, off));
                float mn = fmaxf(m_run[mt][p], m4);
                alpha[p] = __expf(m_run[mt][p] - mn);
                m_run[mt][p] = mn;
                mx[p] = mn;
                rs[p] = 0.f;
            }
            int prow = mt * 16 + (l >> 4) * 4;
            #pragma unroll
            for (int nt = 0; nt < 4; nt++)
                #pragma unroll
                for (int p = 0; p < 4; p++) {
                    float pv = __expf(sc[nt][p] - mx[p]);
                    rs[p] += pv;
                    Ps[w][(prow + p) * 72 + nt * 16 + l15] = (bf16_t)pv;
                }
            #pragma unroll
            for (int p = 0; p < 4; p++) {
                float r = rs[p];
                #pragma unroll
                for (int off = 1; off < 16; off <<= 1)
                    r += __shfl_xor(r, off);
                l_run[mt][p] = l_run[mt][p] * alpha[p] + r;
                #pragma unroll
                for (int dt = 0; dt < 4; dt++) o[mt][dt][p] *= alpha[p];
            }
            bf16x8 ap[2];
            #pragma unroll
            for (int kh = 0; kh < 2; kh++)
                ap[kh] = *(const bf16x8*)&Ps[w][(mt * 16 + l15) * 72
                                                + kh * 32 + lq];
            #pragma unroll
            for (int dt = 0; dt < 4; dt++)
                #pragma unroll
                for (int kh = 0; kh < 2; kh++) {
                    bf16x8 bv = *(const bf16x8*)&Vt[(dt * 16 + l15) * 72
                                                    + kh * 32 + lq];
                    o[mt][dt] = __builtin_amdgcn_mfma_f32_16x16x32_bf16(
                        ap[kh], bv, o[mt][dt], 0, 0, 0);
                }
        }
    }
    #pragma unroll
    for (int mt = 0; mt < 2; mt++)
        #pragma unroll
        for (int dt = 0; dt < 4; dt++)
            #pragma unroll
            for (int p = 0; p < 4; p++) {
                int q = q0 + mt * 16 + (l >> 4) * 4 + p;
                int col = h * 64 + dt * 16 + l15;
                float v = o[mt][dt][p] / l_run[mt][p];
                obuf[((size_t)b * 512 + q) * 512 + col] = (bf16_t)v;
            }
}

// ---------------------------------------------------------------------------
// Convpass down (bf16 h): cpa[row][a] = qgelu(h[row,:] @ dw[:,a] + db[a])
// ---------------------------------------------------------------------------
__global__ __launch_bounds__(256) void k_down(
    const bf16_t* __restrict__ h, const float* __restrict__ dw,
    const float* __restrict__ db, float* __restrict__ outp)
{
    __shared__ float sdw[kC * kAD];
    int t = threadIdx.x;
    for (int i = t; i < kC * kAD; i += 256) sdw[i] = dw[i];
    __syncthreads();
    int gt = blockIdx.x * 256 + t;
    int row = gt >> 3, a = gt & 7;
    const bf16x8* hr = (const bf16x8*)(h + (size_t)row * kC);
    float acc = 0.f;
    for (int k8 = 0; k8 < kC / 8; k8++) {
        bf16x8 hv = hr[k8];
        #pragma unroll
        for (int e = 0; e < 8; e++)
            acc += (float)hv[e] * sdw[(k8 * 8 + e) * kAD + a];
    }
    outp[gt] = qgelu_f(acc + db[a]);
}

// ---------------------------------------------------------------------------
// 3x3x3 SAME conv over 8x8x8, 8->8 ch, + bias, qgelu
// ---------------------------------------------------------------------------
__global__ __launch_bounds__(512) void k_conv(
    const float* __restrict__ inp, const float* __restrict__ cw,
    const float* __restrict__ cb, float* __restrict__ outp)
{
    __shared__ float si[512 * 9];
    __shared__ float sw[8 * 8 * 27];
    int b = blockIdx.x, t = threadIdx.x;
    for (int i = t; i < 512 * 8; i += 512) {
        int n = i >> 3, a = i & 7;
        si[n * 9 + a] = inp[(size_t)b * 4096 + i];
    }
    for (int i = t; i < 1728; i += 512) sw[i] = cw[i];
    __syncthreads();
    int z = t >> 6, y = (t >> 3) & 7, xx = t & 7;
    float acc[8];
    #pragma unroll
    for (int ao = 0; ao < 8; ao++) acc[ao] = cb[ao];
    for (int dz = -1; dz <= 1; dz++) {
        int zz = z + dz; if ((unsigned)zz > 7u) continue;
        for (int dy = -1; dy <= 1; dy++) {
            int yy = y + dy; if ((unsigned)yy > 7u) continue;
            for (int dx = -1; dx <= 1; dx++) {
                int xn = xx + dx; if ((unsigned)xn > 7u) continue;
                int nn = zz * 64 + yy * 8 + xn;
                int wo = ((dz + 1) * 3 + (dy + 1)) * 3 + (dx + 1);
                #pragma unroll
                for (int ai = 0; ai < 8; ai++) {
                    float iv = si[nn * 9 + ai];
                    #pragma unroll
                    for (int ao = 0; ao < 8; ao++)
                        acc[ao] += iv * sw[(ao * 8 + ai) * 27 + wo];
                }
            }
        }
    }
    #pragma unroll
    for (int ao = 0; ao < 8; ao++)
        outp[(size_t)b * 4096 + t * 8 + ao] = qgelu_f(acc[ao]);
}

// ---------------------------------------------------------------------------
// Convpass up: xbuf[row][c] += pa[row,:] @ uw[:,c] + ub[c]
// ---------------------------------------------------------------------------
__global__ __launch_bounds__(256) void k_up(
    const float* __restrict__ pa, const float* __restrict__ uw,
    const float* __restrict__ ub, float* __restrict__ xbuf)
{
    __shared__ float s[8];
    int row = blockIdx.x, t = threadIdx.x;
    if (t < 8) s[t] = pa[(size_t)row * kAD + t];
    __syncthreads();
    #pragma unroll
    for (int rep = 0; rep < 2; rep++) {
        int c = t + rep * 256;
        float acc = ub[c];
        #pragma unroll
        for (int a = 0; a < 8; a++) acc += s[a] * uw[a * kC + c];
        xbuf[(size_t)row * kC + c] += acc;
    }
}

// ---------------------------------------------------------------------------
extern "C" void kernel_launch(void* const* d_in, const int* in_sizes, int n_in,
                              void* d_out, int out_size, void* d_ws, size_t ws_size,
                              hipStream_t stream)
{
    const float* x     = (const float*)d_in[0];
    const float* pos   = (const float*)d_in[1];
    const float* ln1g  = (const float*)d_in[2];
    const float* ln1b  = (const float*)d_in[3];
    const float* qkvw  = (const float*)d_in[4];
    const float* projw = (const float*)d_in[5];
    const float* projb = (const float*)d_in[6];
    const float* dw1   = (const float*)d_in[7];
    const float* db1   = (const float*)d_in[8];
    const float* cw1   = (const float*)d_in[9];
    const float* cb1   = (const float*)d_in[10];
    const float* uw1   = (const float*)d_in[11];
    const float* ub1   = (const float*)d_in[12];
    const float* ln2g  = (const float*)d_in[13];
    const float* ln2b  = (const float*)d_in[14];
    const float* fw1   = (const float*)d_in[15];
    const float* fb1   = (const float*)d_in[16];
    const float* fw2   = (const float*)d_in[17];
    const float* fb2   = (const float*)d_in[18];
    const float* dw2   = (const float*)d_in[19];
    const float* db2   = (const float*)d_in[20];
    const float* cw2   = (const float*)d_in[21];
    const float* cb2   = (const float*)d_in[22];
    const float* uw2   = (const float*)d_in[23];
    const float* ub2   = (const float*)d_in[24];
    float* out = (float*)d_out;

    char* wsb = (char*)d_ws;
    float*  xbuf = (float*)wsb;
    bf16_t* hb   = (bf16_t*)(wsb + 33554432);
    bf16_t* obuf = (bf16_t*)(wsb + 50331648);
    bf16_t* qkvb = (bf16_t*)(wsb + 67108864);
    bf16_t* midb = (bf16_t*)(wsb + 50331648);   // stage-3 alias: [16384][2048]
    bf16_t* qkvT = (bf16_t*)(wsb + 117440512);  // [1536][512]
    bf16_t* projT= (bf16_t*)(wsb + 119013376);  // [512][512]
    bf16_t* fw1T = (bf16_t*)(wsb + 119537664);  // [4096][512]
    bf16_t* fw2T = (bf16_t*)(wsb + 123731968);  // [512][4096]
    float*  cpa  = (float*)(wsb + 127926272);
    float*  cpb  = (float*)(wsb + 128450560);

    // all weight transposes (fp32 -> bf16 B^T form), one dispatch
    k_transpose_all<<<5120, 256, 0, stream>>>(
        qkvw, projw, fw1, fw2, qkvT, projT, fw1T, fw2T);

    // stage 1: xbuf = x + pos; hb = LN1(xbuf)
    k_addln<<<kBN, 256, 0, stream>>>(x, pos, ln1g, ln1b, xbuf, hb,
                                     nullptr, nullptr, nullptr);

    // QKV -> blocked bf16 layout, flash attention, proj (+bias +residual)
    k_gemm<0, false, false, 2, 512, 512, 512, 1536>
        <<<dim3(12, 128), 256, 0, stream>>>(hb, qkvT, nullptr, nullptr, qkvb);
    k_attn<<<kB * kH * 4, 256, 0, stream>>>(qkvb, obuf);
    k_gemm<0, true, true, 0, 512, 512, 512, 512>
        <<<dim3(4, 128), 256, 0, stream>>>(obuf, projT, projb, xbuf, xbuf);

    // convpass 1 (on hb): down + conv; up is folded into the next addln
    k_down<<<kBN * kAD / 256, 256, 0, stream>>>(hb, dw1, db1, cpa);
    k_conv<<<kB, 512, 0, stream>>>(cpa, cw1, cb1, cpb);

    // stage 2: xbuf += cp1_up(cpb); hb = LN2(xbuf)
    k_addln<<<kBN, 256, 0, stream>>>(xbuf, nullptr, ln2g, ln2b, xbuf, hb,
                                     cpb, uw1, ub1);

    // convpass 2, accumulate into xbuf
    k_down<<<kBN * kAD / 256, 256, 0, stream>>>(hb, dw2, db2, cpa);
    k_conv<<<kB, 512, 0, stream>>>(cpa, cw2, cb2, cpb);
    k_up<<<kBN, 256, 0, stream>>>(cpb, uw2, ub2, xbuf);

    // FFN, K-chunked (2 x 2048 mid cols), full M=16384 per dispatch.
    k_gemm<2, true, false, 1, 512, 512, 512, 2048>
        <<<dim3(16, 128), 256, 0, stream>>>(hb, fw1T, fb1, nullptr, midb);
    k_gemm<0, false, true, 0, 2048, 2048, 4096, 512>
        <<<dim3(4, 128), 256, 0, stream>>>(midb, fw2T, nullptr, xbuf, xbuf);
    k_gemm<2, true, false, 1, 512, 512, 512, 2048>
        <<<dim3(16, 128), 256, 0, stream>>>(hb, fw1T + (size_t)2048 * 512,
                                            fb1 + 2048, nullptr, midb);
    k_gemm<0, true, true, 0, 2048, 2048, 4096, 512>
        <<<dim3(4, 128), 256, 0, stream>>>(midb, fw2T + 2048, fb2, xbuf, out);
}